// Round 12
// baseline (1144.419 us; speedup 1.0000x reference)
//
#include <hip/hip_runtime.h>
#include <hip/hip_bf16.h>
#include <math.h>

// B=4, M=2048, D=512, H=8. Heads processed in groups of G (G=4 on this harness).

typedef __attribute__((ext_vector_type(8))) __bf16 bf16x8;
typedef __attribute__((ext_vector_type(4))) __bf16 bf16x4;
typedef __attribute__((ext_vector_type(4))) float f32x4;

#define MFMA16(a, b, c) __builtin_amdgcn_mfma_f32_16x16x32_bf16((a), (b), (c), 0, 0, 0)

__device__ __forceinline__ void g2l16(const void* g, void* l) {
  __builtin_amdgcn_global_load_lds((const __attribute__((address_space(1))) void*)g,
                                   (__attribute__((address_space(3))) void*)l, 16, 0, 0);
}

// ---------------- fused prep: all fp32->bf16 casts + RoPE tables ----------------
__global__ void prep_k(const float* __restrict__ x, const float* __restrict__ wq,
                       const float* __restrict__ wk, const float* __restrict__ wv,
                       const float* __restrict__ wo,
                       __bf16* __restrict__ xb, __bf16* __restrict__ wqb,
                       __bf16* __restrict__ wkb, __bf16* __restrict__ wvb,
                       __bf16* __restrict__ wob,
                       float* __restrict__ ct, float* __restrict__ st) {
  int i = blockIdx.x * 256 + threadIdx.x;
  if (i < 3145728) {
    const float* src;
    __bf16* dst;
    int off = i;
    if (i < 1048576) { src = x; dst = xb; }
    else if (i < 1572864) { src = wq; dst = wqb; off = i - 1048576; }
    else if (i < 2097152) { src = wk; dst = wkb; off = i - 1572864; }
    else if (i < 2621440) { src = wv; dst = wvb; off = i - 2097152; }
    else { src = wo; dst = wob; off = i - 2621440; }
    float4 f = reinterpret_cast<const float4*>(src)[off];
    bf16x4 o;
    o.x = (__bf16)f.x; o.y = (__bf16)f.y; o.z = (__bf16)f.z; o.w = (__bf16)f.w;
    reinterpret_cast<bf16x4*>(dst)[off] = o;
  } else {
    int idx = i - 3145728;  // 2048*256
    int m = idx >> 8, j = idx & 255;
    float e = (-2.0f * ((float)j - 1.0f) / 512.0f) * 13.287712379549449f;  // log2(1e4)
    float theta = exp2f(e);
    float ang = (float)m * theta;
    float s, c;
    sincosf(ang, &s, &c);
    ct[idx] = c;
    st[idx] = s;
  }
}

// ---------------- QKV projection: z = which*G + hl; V written directly transposed ----------------
__global__ __launch_bounds__(256, 2) void qkv_gemm_k(
    const __bf16* __restrict__ Xb,
    const __bf16* __restrict__ Wqb, const __bf16* __restrict__ Wkb, const __bf16* __restrict__ Wvb,
    const float* __restrict__ ct, const float* __restrict__ st,
    __bf16* __restrict__ Q, __bf16* __restrict__ K, __bf16* __restrict__ VT,
    int G, int lg, int h0) {
  const int z = blockIdx.z;
  const int which = z >> lg, hl = z & (G - 1);
  const int h = h0 + hl;
  const __bf16* W = (which == 0 ? Wqb : which == 1 ? Wkb : Wvb) + (size_t)h * 262144;

  const int mbase = blockIdx.x * 128;
  const int nbase = blockIdx.y * 128;

  __shared__ alignas(16) __bf16 As[128 * 64];
  __shared__ alignas(16) __bf16 Bs[128 * 64];

  const int tid = threadIdx.x;
  const int lane = tid & 63, wid = tid >> 6;
  const int wr = wid >> 1, wc = wid & 1;
  const int l15 = lane & 15, l4 = lane >> 4;

  f32x4 acc[4][4];
#pragma unroll
  for (int i = 0; i < 4; i++)
#pragma unroll
    for (int j = 0; j < 4; j++) acc[i][j] = f32x4{0.f, 0.f, 0.f, 0.f};

  for (int kt = 0; kt < 8; ++kt) {
    const int kb = kt * 64;
#pragma unroll
    for (int i = 0; i < 4; i++) {
      int chunk = i * 256 + tid;
      int row = chunk >> 3, col = (chunk & 7) * 8;
      g2l16(Xb + (size_t)(mbase + row) * 512 + kb + col, As + (i * 256 + (tid & ~63)) * 8);
    }
#pragma unroll
    for (int i = 0; i < 4; i++) {
      int chunk = i * 256 + tid;
      int row = chunk >> 3, col = (chunk & 7) * 8;
      g2l16(W + (size_t)(nbase + row) * 512 + kb + col, Bs + (i * 256 + (tid & ~63)) * 8);
    }
    __syncthreads();
#pragma unroll
    for (int kk = 0; kk < 2; ++kk) {
      bf16x8 a[4], b[4];
#pragma unroll
      for (int i = 0; i < 4; i++)
        a[i] = *reinterpret_cast<const bf16x8*>(As + (wr * 64 + i * 16 + l15) * 64 + kk * 32 + l4 * 8);
#pragma unroll
      for (int j = 0; j < 4; j++)
        b[j] = *reinterpret_cast<const bf16x8*>(Bs + (wc * 64 + j * 16 + l15) * 64 + kk * 32 + l4 * 8);
#pragma unroll
      for (int i = 0; i < 4; i++)
#pragma unroll
        for (int j = 0; j < 4; j++) acc[i][j] = MFMA16(a[i], b[j], acc[i][j]);
    }
    __syncthreads();
  }

  if (which == 2) {
    const int b_ = mbase >> 11;
    const int mloc = mbase & 2047;
    __bf16* Tgw = VT + (size_t)(b_ * G + hl) * 512 * 2048;
#pragma unroll
    for (int i = 0; i < 4; i++) {
#pragma unroll
      for (int j = 0; j < 4; j++) {
        const int col = nbase + wc * 64 + j * 16 + l15;
        const int m0 = mloc + wr * 64 + i * 16 + l4 * 4;
        bf16x4 pk;
        pk.x = (__bf16)acc[i][j][0];
        pk.y = (__bf16)acc[i][j][1];
        pk.z = (__bf16)acc[i][j][2];
        pk.w = (__bf16)acc[i][j][3];
        *reinterpret_cast<bf16x4*>(&Tgw[(size_t)col * 2048 + m0]) = pk;
      }
    }
  } else {
    __bf16* Out = which ? K : Q;
#pragma unroll
    for (int i = 0; i < 4; i++) {
#pragma unroll
      for (int j = 0; j < 4; j++) {
        const int col = nbase + wc * 64 + j * 16 + l15;
#pragma unroll
        for (int r = 0; r < 4; r++) {
          const int rowg = mbase + wr * 64 + i * 16 + l4 * 4 + r;
          const int b_ = rowg >> 11, m = rowg & 2047;
          float v = acc[i][j][r];
          float pv = __shfl_xor(v, 1, 64);
          float c = ct[m * 256 + (col >> 1)];
          float s = st[m * 256 + (col >> 1)];
          v = (col & 1) ? (v * c - pv * s) : (v * c + pv * s);
          Out[(size_t)((b_ * G + hl) * 2048 + m) * 512 + col] = (__bf16)v;
        }
      }
    }
  }
}

// ---------------- flash v1 (R10 proven: 360us/launch) ----------------
__global__ __launch_bounds__(512) void flash_attn_k(
    const __bf16* __restrict__ Q, const __bf16* __restrict__ K, const __bf16* __restrict__ VT,
    __bf16* __restrict__ O, int G, int lg) {
  const int bhN = 4 * G;
  const int L = blockIdx.x + 16 * blockIdx.y;
  const int half = L / (8 * bhN);
  const int r_ = L % (8 * bhN);
  const int bh = r_ % bhN;
  const int p_ = r_ / bhN;
  const int qblk = half ? (15 - p_) : p_;
  const int b = bh >> lg, hl = bh & (G - 1);
  const int tid = threadIdx.x, lane = tid & 63, wid = tid >> 6;
  const int l15 = lane & 15, l4 = lane >> 4;
  const int qw = qblk * 128 + wid * 16;

  __shared__ alignas(16) __bf16 Ks[32 * 512];
  __shared__ alignas(16) __bf16 Vts[512 * 32];
  __shared__ alignas(16) __bf16 Ps[8][16 * 32];

  const __bf16* Qg = Q + ((size_t)bh * 2048 + qw) * 512;
  const __bf16* Kg = K + (size_t)bh * 2048 * 512;
  const __bf16* Tg = VT + (size_t)bh * 512 * 2048;

  bf16x8 qf[16];
#pragma unroll
  for (int c = 0; c < 16; c++)
    qf[c] = *reinterpret_cast<const bf16x8*>(Qg + l15 * 512 + c * 32 + l4 * 8);

  f32x4 acc[32];
#pragma unroll
  for (int n = 0; n < 32; n++) acc[n] = f32x4{0.f, 0.f, 0.f, 0.f};
  float mrow[4] = {-INFINITY, -INFINITY, -INFINITY, -INFINITY};
  float lrow[4] = {0.f, 0.f, 0.f, 0.f};

  const float scale = 0.04419417382415922f;
  const int ntiles = qblk * 4 + 4;

  for (int kt = 0; kt < ntiles; ++kt) {
    const int kb = kt * 32;
#pragma unroll
    for (int i = 0; i < 4; i++) {
      int chunk = i * 512 + tid;
      int row = chunk >> 6, c16 = chunk & 63;
      g2l16(Kg + (size_t)(kb + row) * 512 + ((c16 ^ (row & 7)) << 3),
            Ks + (i * 512 + (tid & ~63)) * 8);
    }
#pragma unroll
    for (int i = 0; i < 4; i++) {
      int chunk = i * 512 + tid;
      int row = chunk >> 2, c4 = chunk & 3;
      g2l16(Tg + (size_t)row * 2048 + kb + ((c4 ^ (row & 3)) << 3),
            Vts + (i * 512 + (tid & ~63)) * 8);
    }
    __syncthreads();

    f32x4 sv0 = f32x4{0.f, 0.f, 0.f, 0.f}, sv1 = f32x4{0.f, 0.f, 0.f, 0.f};
#pragma unroll
    for (int c = 0; c < 16; c++) {
      const int off = c * 32 + l4 * 8;
      const int r0 = l15, r1 = 16 + l15;
      bf16x8 b0 = *reinterpret_cast<const bf16x8*>(Ks + r0 * 512 + (off ^ ((r0 & 7) << 3)));
      bf16x8 b1 = *reinterpret_cast<const bf16x8*>(Ks + r1 * 512 + (off ^ ((r1 & 7) << 3)));
      sv0 = MFMA16(qf[c], b0, sv0);
      sv1 = MFMA16(qf[c], b1, sv1);
    }

    float alpha[4];
#pragma unroll
    for (int r = 0; r < 4; r++) {
      const int qg = qw + l4 * 4 + r;
      float s0 = sv0[r] * scale;
      float s1 = sv1[r] * scale;
      if (kb + l15 > qg) s0 = -INFINITY;
      if (kb + 16 + l15 > qg) s1 = -INFINITY;
      float mx = fmaxf(s0, s1);
      mx = fmaxf(mx, __shfl_xor(mx, 1, 64));
      mx = fmaxf(mx, __shfl_xor(mx, 2, 64));
      mx = fmaxf(mx, __shfl_xor(mx, 4, 64));
      mx = fmaxf(mx, __shfl_xor(mx, 8, 64));
      const float mn = fmaxf(mrow[r], mx);
      const float p0 = __expf(s0 - mn);
      const float p1 = __expf(s1 - mn);
      const float a_ = __expf(mrow[r] - mn);
      float rs = p0 + p1;
      rs += __shfl_xor(rs, 1, 64);
      rs += __shfl_xor(rs, 2, 64);
      rs += __shfl_xor(rs, 4, 64);
      rs += __shfl_xor(rs, 8, 64);
      lrow[r] = lrow[r] * a_ + rs;
      mrow[r] = mn;
      alpha[r] = a_;
      __bf16* P = &Ps[wid][0];
      P[(l4 * 4 + r) * 32 + l15] = (__bf16)p0;
      P[(l4 * 4 + r) * 32 + 16 + l15] = (__bf16)p1;
    }
#pragma unroll
    for (int n = 0; n < 32; n++) {
#pragma unroll
      for (int r = 0; r < 4; r++) acc[n][r] *= alpha[r];
    }
    bf16x8 pf = *reinterpret_cast<const bf16x8*>(&Ps[wid][0] + l15 * 32 + l4 * 8);
#pragma unroll
    for (int n = 0; n < 32; n++) {
      const int row = n * 16 + l15;
      bf16x8 vb = *reinterpret_cast<const bf16x8*>(Vts + row * 32 + ((l4 * 8) ^ ((row & 3) << 3)));
      acc[n] = MFMA16(pf, vb, acc[n]);
    }
    __syncthreads();
  }

#pragma unroll
  for (int r = 0; r < 4; r++) {
    const int qg = qw + l4 * 4 + r;
    const float inv = 1.0f / lrow[r];
    __bf16* Og = O + ((size_t)(b * 2048 + qg) * (512 * G) + hl * 512);
#pragma unroll
    for (int n = 0; n < 32; n++) Og[n * 16 + l15] = (__bf16)(acc[n][r] * inv);
  }
}

// ---------------- flash v2 (A/B experiment): PV d-split, aligned padded stride 40 ----------------
// Wave w: softmax rows [16w,16w+16); PV d-slice [64w,64w+64) for all 128 rows via shared
// Ps[128][40] + Al[128]. V reg-staged -> Vts[512][40] (80B stride, 16B-aligned, 20-bank spread).
// launch_bounds(512,1): up to 256 VGPR -> no scratch spill (R8's failure mode).
__global__ __launch_bounds__(512, 1) void flash_attn2_k(
    const __bf16* __restrict__ Q, const __bf16* __restrict__ K, const __bf16* __restrict__ VT,
    __bf16* __restrict__ O, int G, int lg) {
  const int bhN = 4 * G;
  const int L = blockIdx.x + 16 * blockIdx.y;
  const int half = L / (8 * bhN);
  const int r_ = L % (8 * bhN);
  const int bh = r_ % bhN;
  const int p_ = r_ / bhN;
  const int qblk = half ? (15 - p_) : p_;
  const int b = bh >> lg, hl = bh & (G - 1);
  const int tid = threadIdx.x, lane = tid & 63, wid = tid >> 6;
  const int l15 = lane & 15, l4 = lane >> 4;
  const int qbase = qblk * 128;
  const int qw = qbase + wid * 16;

  __shared__ alignas(16) __bf16 Ks[32 * 512];   // 32KB, 3-bit XOR chunk swizzle
  __shared__ alignas(16) __bf16 Vts[512 * 40];  // 40KB, aligned padded
  __shared__ alignas(16) __bf16 Ps[128 * 40];   // 10KB, shared P
  __shared__ alignas(16) float Al[128];

  const __bf16* Qg = Q + ((size_t)bh * 2048 + qw) * 512;
  const __bf16* Kg = K + (size_t)bh * 2048 * 512;
  const __bf16* Tg = VT + (size_t)bh * 512 * 2048;
  const float scale = 0.04419417382415922f;

  bf16x8 qf[16];
#pragma unroll
  for (int c = 0; c < 16; c++)
    qf[c] = *reinterpret_cast<const bf16x8*>(Qg + l15 * 512 + c * 32 + l4 * 8);

  f32x4 acc[8][4];  // [q-frag 0..7][d-frag 0..3] for d-slice 64*wid
#pragma unroll
  for (int i = 0; i < 8; i++)
#pragma unroll
    for (int j = 0; j < 4; j++) acc[i][j] = f32x4{0.f, 0.f, 0.f, 0.f};
  float mrow[4] = {-INFINITY, -INFINITY, -INFINITY, -INFINITY};
  float lrow[4] = {0.f, 0.f, 0.f, 0.f};

  const int nt = 4 * qblk + 4;
  bf16x8 vreg[4];

  auto stageK = [&](int kt2) {
#pragma unroll
    for (int i = 0; i < 4; i++) {
      int chunk = i * 512 + tid;
      int row = chunk >> 6, c16 = chunk & 63;
      g2l16(Kg + (size_t)(kt2 * 32 + row) * 512 + ((c16 ^ (row & 7)) << 3),
            Ks + (i * 512 + (tid & ~63)) * 8);
    }
  };
  auto loadV = [&](int kt2) {
#pragma unroll
    for (int i = 0; i < 4; i++) {
      int chunk = i * 512 + tid;
      vreg[i] = *reinterpret_cast<const bf16x8*>(
          Tg + (size_t)(chunk >> 2) * 2048 + kt2 * 32 + (chunk & 3) * 8);
    }
  };

  stageK(0);
  loadV(0);

  for (int kt = 0; kt < nt; ++kt) {
    const int kb = kt * 32;
    __syncthreads();  // drains K(kt)/V(kt) loads (issued one phase ago); prev PV done

    // commit V(kt) regs -> padded LDS
#pragma unroll
    for (int i = 0; i < 4; i++) {
      int chunk = i * 512 + tid;
      *reinterpret_cast<bf16x8*>(&Vts[(chunk >> 2) * 40 + (chunk & 3) * 8]) = vreg[i];
    }

    // QK^T for this wave's 16 rows
    f32x4 sv0 = f32x4{0.f, 0.f, 0.f, 0.f}, sv1 = f32x4{0.f, 0.f, 0.f, 0.f};
    __builtin_amdgcn_s_setprio(1);
#pragma unroll
    for (int c = 0; c < 16; c++) {
      const int off = c * 32 + l4 * 8;
      const int r0 = l15, r1 = 16 + l15;
      bf16x8 b0 = *reinterpret_cast<const bf16x8*>(Ks + r0 * 512 + (off ^ ((r0 & 7) << 3)));
      bf16x8 b1 = *reinterpret_cast<const bf16x8*>(Ks + r1 * 512 + (off ^ ((r1 & 7) << 3)));
      sv0 = MFMA16(qf[c], b0, sv0);
      sv1 = MFMA16(qf[c], b1, sv1);
    }
    __builtin_amdgcn_s_setprio(0);

    // online softmax (defer-max THR=8)
    float mx[4];
#pragma unroll
    for (int r = 0; r < 4; r++) {
      const int qg = qw + l4 * 4 + r;
      float s0 = sv0[r] * scale;
      float s1 = sv1[r] * scale;
      if (kb + l15 > qg) s0 = -INFINITY;
      if (kb + 16 + l15 > qg) s1 = -INFINITY;
      sv0[r] = s0; sv1[r] = s1;
      float m_ = fmaxf(s0, s1);
      m_ = fmaxf(m_, __shfl_xor(m_, 1, 64));
      m_ = fmaxf(m_, __shfl_xor(m_, 2, 64));
      m_ = fmaxf(m_, __shfl_xor(m_, 4, 64));
      m_ = fmaxf(m_, __shfl_xor(m_, 8, 64));
      mx[r] = m_;
    }
    bool need = (mx[0] > mrow[0] + 8.f) || (mx[1] > mrow[1] + 8.f) ||
                (mx[2] > mrow[2] + 8.f) || (mx[3] > mrow[3] + 8.f);
    float al[4] = {1.f, 1.f, 1.f, 1.f};
    if (need) {
#pragma unroll
      for (int r = 0; r < 4; r++) {
        float mn = fmaxf(mrow[r], mx[r]);
        al[r] = __expf(mrow[r] - mn);
        lrow[r] *= al[r];
        mrow[r] = mn;
      }
    }
#pragma unroll
    for (int r = 0; r < 4; r++) {
      float p0 = __expf(sv0[r] - mrow[r]);
      float p1 = __expf(sv1[r] - mrow[r]);
      float rs = p0 + p1;
      rs += __shfl_xor(rs, 1, 64);
      rs += __shfl_xor(rs, 2, 64);
      rs += __shfl_xor(rs, 4, 64);
      rs += __shfl_xor(rs, 8, 64);
      lrow[r] += rs;
      const int prow = wid * 16 + l4 * 4 + r;
      Ps[prow * 40 + l15] = (__bf16)p0;
      Ps[prow * 40 + 16 + l15] = (__bf16)p1;
      if (l15 == 0) Al[prow] = al[r];
    }

    int anyresc = __syncthreads_or((int)need);  // Ps/Al/Vts visible

    // prefetch next tile (flies through rescale+PV, drained at next top barrier)
    if (kt + 1 < nt) {
      stageK(kt + 1);
      loadV(kt + 1);
    }

    if (anyresc) {
#pragma unroll
      for (int i = 0; i < 8; i++) {
        f32x4 a4 = *reinterpret_cast<const f32x4*>(&Al[i * 16 + l4 * 4]);
#pragma unroll
        for (int j = 0; j < 4; j++) {
#pragma unroll
          for (int r = 0; r < 4; r++) acc[i][j][r] *= a4[r];
        }
      }
    }

    // PV: wave owns d-slice [64*wid, +64) for all 128 q rows
    const int d0 = wid * 64;
    __builtin_amdgcn_s_setprio(1);
#pragma unroll
    for (int qh = 0; qh < 2; ++qh) {
      bf16x8 pA[4];
#pragma unroll
      for (int i = 0; i < 4; i++)
        pA[i] = *reinterpret_cast<const bf16x8*>(&Ps[((qh * 4 + i) * 16 + l15) * 40 + l4 * 8]);
#pragma unroll
      for (int j = 0; j < 4; j++) {
        bf16x8 vB = *reinterpret_cast<const bf16x8*>(&Vts[(d0 + j * 16 + l15) * 40 + l4 * 8]);
#pragma unroll
        for (int i = 0; i < 4; i++)
          acc[qh * 4 + i][j] = MFMA16(pA[i], vB, acc[qh * 4 + i][j]);
      }
    }
    __builtin_amdgcn_s_setprio(0);
  }

  // epilogue: share 1/l via Al, write O
  __syncthreads();
#pragma unroll
  for (int r = 0; r < 4; r++)
    if (l15 == 0) Al[wid * 16 + l4 * 4 + r] = 1.0f / lrow[r];
  __syncthreads();
  const int d0 = wid * 64;
#pragma unroll
  for (int i = 0; i < 8; i++) {
    f32x4 inv4 = *reinterpret_cast<const f32x4*>(&Al[i * 16 + l4 * 4]);
#pragma unroll
    for (int r = 0; r < 4; r++) {
      const int qg = qbase + i * 16 + l4 * 4 + r;
      __bf16* Og = O + ((size_t)(b * 2048 + qg) * (512 * G) + hl * 512 + d0);
#pragma unroll
      for (int j = 0; j < 4; j++) Og[j * 16 + l15] = (__bf16)(acc[i][j][r] * inv4[r]);
    }
  }
}

// ---------------- output projection: 128x64 tile ----------------
__global__ __launch_bounds__(256) void out_gemm_k(
    const __bf16* __restrict__ A, const __bf16* __restrict__ Wo,
    const float* __restrict__ bias, float* __restrict__ Y, int G, int first) {
  const int AS = 512 * G;
  const int mbase = blockIdx.x * 128, nbase = blockIdx.y * 64;
  __shared__ alignas(16) __bf16 As[128 * 64];
  __shared__ alignas(16) __bf16 Bs[64 * 64];
  const int tid = threadIdx.x;
  const int lane = tid & 63, wid = tid >> 6;
  const int wr = wid >> 1, wc = wid & 1;
  const int l15 = lane & 15, l4 = lane >> 4;

  f32x4 acc[4][2];
#pragma unroll
  for (int i = 0; i < 4; i++)
#pragma unroll
    for (int j = 0; j < 2; j++) acc[i][j] = f32x4{0.f, 0.f, 0.f, 0.f};

  const int nkt = 8 * G;
  for (int kt = 0; kt < nkt; ++kt) {
    const int kb = kt * 64;
#pragma unroll
    for (int i = 0; i < 4; i++) {
      int chunk = i * 256 + tid;
      int row = chunk >> 3, col = (chunk & 7) * 8;
      g2l16(A + (size_t)(mbase + row) * AS + kb + col, As + (i * 256 + (tid & ~63)) * 8);
    }
#pragma unroll
    for (int i = 0; i < 2; i++) {
      int chunk = i * 256 + tid;
      int row = chunk >> 3, col = (chunk & 7) * 8;
      g2l16(Wo + (size_t)(nbase + row) * 4096 + kb + col, Bs + (i * 256 + (tid & ~63)) * 8);
    }
    __syncthreads();
#pragma unroll
    for (int kk = 0; kk < 2; ++kk) {
      bf16x8 a[4], b[2];
#pragma unroll
      for (int i = 0; i < 4; i++)
        a[i] = *reinterpret_cast<const bf16x8*>(As + (wr * 64 + i * 16 + l15) * 64 + kk * 32 + l4 * 8);
#pragma unroll
      for (int j = 0; j < 2; j++)
        b[j] = *reinterpret_cast<const bf16x8*>(Bs + (wc * 32 + j * 16 + l15) * 64 + kk * 32 + l4 * 8);
#pragma unroll
      for (int i = 0; i < 4; i++)
#pragma unroll
        for (int j = 0; j < 2; j++) acc[i][j] = MFMA16(a[i], b[j], acc[i][j]);
    }
    __syncthreads();
  }

#pragma unroll
  for (int i = 0; i < 4; i++) {
#pragma unroll
    for (int j = 0; j < 2; j++) {
      const int col = nbase + wc * 32 + j * 16 + l15;
#pragma unroll
      for (int r = 0; r < 4; r++) {
        const int row = mbase + wr * 64 + i * 16 + l4 * 4 + r;
        float prev = first ? bias[col] : Y[(size_t)row * 512 + col];
        Y[(size_t)row * 512 + col] = prev + acc[i][j][r];
      }
    }
  }
}

extern "C" void kernel_launch(void* const* d_in, const int* in_sizes, int n_in,
                              void* d_out, int out_size, void* d_ws, size_t ws_size,
                              hipStream_t stream) {
  (void)in_sizes; (void)n_in; (void)out_size;
  const float* x = (const float*)d_in[0];
  const float* wq = (const float*)d_in[1];
  const float* wk = (const float*)d_in[2];
  const float* wv = (const float*)d_in[3];
  const float* wo = (const float*)d_in[4];
  const float* bo = (const float*)d_in[5];
  float* y = (float*)d_out;

  char* base = (char*)d_ws;
  size_t off = 0;
  auto alloc = [&](size_t bytes) -> void* {
    void* p = base + off;
    off += (bytes + 255) & ~(size_t)255;
    return p;
  };
  __bf16* xb = (__bf16*)alloc((size_t)8192 * 512 * 2);
  __bf16* wqb = (__bf16*)alloc((size_t)8 * 512 * 512 * 2);
  __bf16* wkb = (__bf16*)alloc((size_t)8 * 512 * 512 * 2);
  __bf16* wvb = (__bf16*)alloc((size_t)8 * 512 * 512 * 2);
  __bf16* wob = (__bf16*)alloc((size_t)512 * 4096 * 2);
  float* ct = (float*)alloc((size_t)2048 * 256 * 4);
  float* st = (float*)alloc((size_t)2048 * 256 * 4);
  const size_t persist = off;

  int G = 0, lg = 0;
  for (int g = 8, l = 3; g >= 1; g >>= 1, --l) {
    size_t T = ((size_t)g * 4 * 2048 * 512 * 2 + 255) & ~(size_t)255;
    if (persist + 4 * T <= ws_size) { G = g; lg = l; break; }
  }
  if (G == 0) return;

  size_t T = ((size_t)G * 4 * 2048 * 512 * 2 + 255) & ~(size_t)255;
  __bf16* Qb = (__bf16*)(base + persist);
  __bf16* Kb = (__bf16*)(base + persist + T);
  __bf16* VTb = (__bf16*)(base + persist + 2 * T);
  __bf16* Ob = (__bf16*)(base + persist + 3 * T);

  prep_k<<<14336, 256, 0, stream>>>(x, wq, wk, wv, wo, xb, wqb, wkb, wvb, wob, ct, st);

  for (int h0 = 0; h0 < 8; h0 += G) {
    qkv_gemm_k<<<dim3(64, 4, 3 * G), 256, 0, stream>>>(xb, wqb, wkb, wvb, ct, st,
                                                       Qb, Kb, VTb, G, lg, h0);
    // In-run A/B: first group runs proven v1; second group runs the d-split v2.
    if (h0 == 0)
      flash_attn_k<<<dim3(16, 4 * G), 512, 0, stream>>>(Qb, Kb, VTb, Ob, G, lg);
    else
      flash_attn2_k<<<dim3(16, 4 * G), 512, 0, stream>>>(Qb, Kb, VTb, Ob, G, lg);
    out_gemm_k<<<dim3(64, 8), 256, 0, stream>>>(Ob, wob + h0 * 512, bo, y, G, h0 == 0);
  }
}

// Round 13
// 699.655 us; speedup vs baseline: 1.6357x; 1.6357x over previous
//
#include <hip/hip_runtime.h>
#include <hip/hip_bf16.h>
#include <math.h>

// B=4, M=2048, D=512, H=8. Heads in groups of G (G=4 on this harness).

typedef __attribute__((ext_vector_type(8))) __bf16 bf16x8;
typedef __attribute__((ext_vector_type(4))) __bf16 bf16x4;
typedef __attribute__((ext_vector_type(4))) float f32x4;

#define MFMA16(a, b, c) __builtin_amdgcn_mfma_f32_16x16x32_bf16((a), (b), (c), 0, 0, 0)

__device__ __forceinline__ void g2l16(const void* g, void* l) {
  __builtin_amdgcn_global_load_lds((const __attribute__((address_space(1))) void*)g,
                                   (__attribute__((address_space(3))) void*)l, 16, 0, 0);
}

// ---------------- fused prep: all fp32->bf16 casts + RoPE tables ----------------
__global__ void prep_k(const float* __restrict__ x, const float* __restrict__ wq,
                       const float* __restrict__ wk, const float* __restrict__ wv,
                       const float* __restrict__ wo,
                       __bf16* __restrict__ xb, __bf16* __restrict__ wqb,
                       __bf16* __restrict__ wkb, __bf16* __restrict__ wvb,
                       __bf16* __restrict__ wob,
                       float* __restrict__ ct, float* __restrict__ st) {
  int i = blockIdx.x * 256 + threadIdx.x;
  if (i < 3145728) {
    const float* src;
    __bf16* dst;
    int off = i;
    if (i < 1048576) { src = x; dst = xb; }
    else if (i < 1572864) { src = wq; dst = wqb; off = i - 1048576; }
    else if (i < 2097152) { src = wk; dst = wkb; off = i - 1572864; }
    else if (i < 2621440) { src = wv; dst = wvb; off = i - 2097152; }
    else { src = wo; dst = wob; off = i - 2621440; }
    float4 f = reinterpret_cast<const float4*>(src)[off];
    bf16x4 o;
    o.x = (__bf16)f.x; o.y = (__bf16)f.y; o.z = (__bf16)f.z; o.w = (__bf16)f.w;
    reinterpret_cast<bf16x4*>(dst)[off] = o;
  } else {
    int idx = i - 3145728;  // 2048*256
    int m = idx >> 8, j = idx & 255;
    float e = (-2.0f * ((float)j - 1.0f) / 512.0f) * 13.287712379549449f;  // log2(1e4)
    float theta = exp2f(e);
    float ang = (float)m * theta;
    float s, c;
    sincosf(ang, &s, &c);
    ct[idx] = c;
    st[idx] = s;
  }
}

// ---------------- QKV projection: z = which*G + hl; V written directly transposed ----------------
__global__ __launch_bounds__(256, 2) void qkv_gemm_k(
    const __bf16* __restrict__ Xb,
    const __bf16* __restrict__ Wqb, const __bf16* __restrict__ Wkb, const __bf16* __restrict__ Wvb,
    const float* __restrict__ ct, const float* __restrict__ st,
    __bf16* __restrict__ Q, __bf16* __restrict__ K, __bf16* __restrict__ VT,
    int G, int lg, int h0) {
  const int z = blockIdx.z;
  const int which = z >> lg, hl = z & (G - 1);
  const int h = h0 + hl;
  const __bf16* W = (which == 0 ? Wqb : which == 1 ? Wkb : Wvb) + (size_t)h * 262144;

  const int mbase = blockIdx.x * 128;
  const int nbase = blockIdx.y * 128;

  __shared__ alignas(16) __bf16 As[128 * 64];
  __shared__ alignas(16) __bf16 Bs[128 * 64];

  const int tid = threadIdx.x;
  const int lane = tid & 63, wid = tid >> 6;
  const int wr = wid >> 1, wc = wid & 1;
  const int l15 = lane & 15, l4 = lane >> 4;

  f32x4 acc[4][4];
#pragma unroll
  for (int i = 0; i < 4; i++)
#pragma unroll
    for (int j = 0; j < 4; j++) acc[i][j] = f32x4{0.f, 0.f, 0.f, 0.f};

  for (int kt = 0; kt < 8; ++kt) {
    const int kb = kt * 64;
#pragma unroll
    for (int i = 0; i < 4; i++) {
      int chunk = i * 256 + tid;
      int row = chunk >> 3, col = (chunk & 7) * 8;
      g2l16(Xb + (size_t)(mbase + row) * 512 + kb + col, As + (i * 256 + (tid & ~63)) * 8);
    }
#pragma unroll
    for (int i = 0; i < 4; i++) {
      int chunk = i * 256 + tid;
      int row = chunk >> 3, col = (chunk & 7) * 8;
      g2l16(W + (size_t)(nbase + row) * 512 + kb + col, Bs + (i * 256 + (tid & ~63)) * 8);
    }
    __syncthreads();
#pragma unroll
    for (int kk = 0; kk < 2; ++kk) {
      bf16x8 a[4], b[4];
#pragma unroll
      for (int i = 0; i < 4; i++)
        a[i] = *reinterpret_cast<const bf16x8*>(As + (wr * 64 + i * 16 + l15) * 64 + kk * 32 + l4 * 8);
#pragma unroll
      for (int j = 0; j < 4; j++)
        b[j] = *reinterpret_cast<const bf16x8*>(Bs + (wc * 64 + j * 16 + l15) * 64 + kk * 32 + l4 * 8);
#pragma unroll
      for (int i = 0; i < 4; i++)
#pragma unroll
        for (int j = 0; j < 4; j++) acc[i][j] = MFMA16(a[i], b[j], acc[i][j]);
    }
    __syncthreads();
  }

  if (which == 2) {
    const int b_ = mbase >> 11;
    const int mloc = mbase & 2047;
    __bf16* Tgw = VT + (size_t)(b_ * G + hl) * 512 * 2048;
#pragma unroll
    for (int i = 0; i < 4; i++) {
#pragma unroll
      for (int j = 0; j < 4; j++) {
        const int col = nbase + wc * 64 + j * 16 + l15;
        const int m0 = mloc + wr * 64 + i * 16 + l4 * 4;
        bf16x4 pk;
        pk.x = (__bf16)acc[i][j][0];
        pk.y = (__bf16)acc[i][j][1];
        pk.z = (__bf16)acc[i][j][2];
        pk.w = (__bf16)acc[i][j][3];
        *reinterpret_cast<bf16x4*>(&Tgw[(size_t)col * 2048 + m0]) = pk;
      }
    }
  } else {
    __bf16* Out = which ? K : Q;
#pragma unroll
    for (int i = 0; i < 4; i++) {
#pragma unroll
      for (int j = 0; j < 4; j++) {
        const int col = nbase + wc * 64 + j * 16 + l15;
#pragma unroll
        for (int r = 0; r < 4; r++) {
          const int rowg = mbase + wr * 64 + i * 16 + l4 * 4 + r;
          const int b_ = rowg >> 11, m = rowg & 2047;
          float v = acc[i][j][r];
          float pv = __shfl_xor(v, 1, 64);
          float c = ct[m * 256 + (col >> 1)];
          float s = st[m * 256 + (col >> 1)];
          v = (col & 1) ? (v * c - pv * s) : (v * c + pv * s);
          Out[(size_t)((b_ * G + hl) * 2048 + m) * 512 + col] = (__bf16)v;
        }
      }
    }
  }
}

// ---------------- causal flash attention (R10 body; SPLIT adds balanced split-K) ----------------
// SPLIT=0: legacy R10 grid (16, 4G). SPLIT=1: 1-D grid 32*bhN; (bh,q,ks) mapping puts
// (q,ks=0) and (15-q,ks=1) on the same CU -> exactly 36 tiles/CU, 2 blocks/CU co-resident.
// ks=0 covers k-tiles [0,2q+2), ks=1 [2q+2,4q+4); each writes normalized partial O + (m,l).
template <int SPLIT>
__global__ __launch_bounds__(512) void flash_attn_k(
    const __bf16* __restrict__ Q, const __bf16* __restrict__ K, const __bf16* __restrict__ VT,
    __bf16* __restrict__ O0, __bf16* __restrict__ O1, float2* __restrict__ Ml,
    int G, int lg) {
  const int bhN = 4 * G;
  int bh, qblk, kt0, kt1, ks;
  if constexpr (SPLIT) {
    const int L = blockIdx.x;
    bh = L % bhN;
    const int s_ = L / bhN;  // 0..31
    ks = (s_ < 16) ? 0 : 1;
    qblk = ks ? (31 - s_) : s_;
    const int hn = 2 * qblk + 2;
    kt0 = ks * hn;
    kt1 = kt0 + hn;
  } else {
    const int L = blockIdx.x + 16 * blockIdx.y;
    const int half = L / (8 * bhN);
    const int r_ = L % (8 * bhN);
    bh = r_ % bhN;
    const int p_ = r_ / bhN;
    qblk = half ? (15 - p_) : p_;
    kt0 = 0;
    kt1 = 4 * qblk + 4;
    ks = 0;
  }
  const int b = bh >> lg, hl = bh & (G - 1);
  const int tid = threadIdx.x, lane = tid & 63, wid = tid >> 6;
  const int l15 = lane & 15, l4 = lane >> 4;
  const int qw = qblk * 128 + wid * 16;

  __shared__ alignas(16) __bf16 Ks[32 * 512];
  __shared__ alignas(16) __bf16 Vts[512 * 32];
  __shared__ alignas(16) __bf16 Ps[8][16 * 32];

  const __bf16* Qg = Q + ((size_t)bh * 2048 + qw) * 512;
  const __bf16* Kg = K + (size_t)bh * 2048 * 512;
  const __bf16* Tg = VT + (size_t)bh * 512 * 2048;

  bf16x8 qf[16];
#pragma unroll
  for (int c = 0; c < 16; c++)
    qf[c] = *reinterpret_cast<const bf16x8*>(Qg + l15 * 512 + c * 32 + l4 * 8);

  f32x4 acc[32];
#pragma unroll
  for (int n = 0; n < 32; n++) acc[n] = f32x4{0.f, 0.f, 0.f, 0.f};
  float mrow[4] = {-INFINITY, -INFINITY, -INFINITY, -INFINITY};
  float lrow[4] = {0.f, 0.f, 0.f, 0.f};

  const float scale = 0.04419417382415922f;  // 1/sqrt(512)

  for (int kt = kt0; kt < kt1; ++kt) {
    const int kb = kt * 32;
#pragma unroll
    for (int i = 0; i < 4; i++) {
      int chunk = i * 512 + tid;
      int row = chunk >> 6, c16 = chunk & 63;
      g2l16(Kg + (size_t)(kb + row) * 512 + ((c16 ^ (row & 7)) << 3),
            Ks + (i * 512 + (tid & ~63)) * 8);
    }
#pragma unroll
    for (int i = 0; i < 4; i++) {
      int chunk = i * 512 + tid;
      int row = chunk >> 2, c4 = chunk & 3;
      g2l16(Tg + (size_t)row * 2048 + kb + ((c4 ^ (row & 3)) << 3),
            Vts + (i * 512 + (tid & ~63)) * 8);
    }
    __syncthreads();

    f32x4 sv0 = f32x4{0.f, 0.f, 0.f, 0.f}, sv1 = f32x4{0.f, 0.f, 0.f, 0.f};
#pragma unroll
    for (int c = 0; c < 16; c++) {
      const int off = c * 32 + l4 * 8;
      const int r0 = l15, r1 = 16 + l15;
      bf16x8 b0 = *reinterpret_cast<const bf16x8*>(Ks + r0 * 512 + (off ^ ((r0 & 7) << 3)));
      bf16x8 b1 = *reinterpret_cast<const bf16x8*>(Ks + r1 * 512 + (off ^ ((r1 & 7) << 3)));
      sv0 = MFMA16(qf[c], b0, sv0);
      sv1 = MFMA16(qf[c], b1, sv1);
    }

    float alpha[4];
#pragma unroll
    for (int r = 0; r < 4; r++) {
      const int qg = qw + l4 * 4 + r;
      float s0 = sv0[r] * scale;
      float s1 = sv1[r] * scale;
      if (kb + l15 > qg) s0 = -INFINITY;
      if (kb + 16 + l15 > qg) s1 = -INFINITY;
      float mx = fmaxf(s0, s1);
      mx = fmaxf(mx, __shfl_xor(mx, 1, 64));
      mx = fmaxf(mx, __shfl_xor(mx, 2, 64));
      mx = fmaxf(mx, __shfl_xor(mx, 4, 64));
      mx = fmaxf(mx, __shfl_xor(mx, 8, 64));
      const float mn = fmaxf(mrow[r], mx);
      const float p0 = __expf(s0 - mn);
      const float p1 = __expf(s1 - mn);
      const float a_ = __expf(mrow[r] - mn);
      float rs = p0 + p1;
      rs += __shfl_xor(rs, 1, 64);
      rs += __shfl_xor(rs, 2, 64);
      rs += __shfl_xor(rs, 4, 64);
      rs += __shfl_xor(rs, 8, 64);
      lrow[r] = lrow[r] * a_ + rs;
      mrow[r] = mn;
      alpha[r] = a_;
      __bf16* P = &Ps[wid][0];
      P[(l4 * 4 + r) * 32 + l15] = (__bf16)p0;
      P[(l4 * 4 + r) * 32 + 16 + l15] = (__bf16)p1;
    }
#pragma unroll
    for (int n = 0; n < 32; n++) {
#pragma unroll
      for (int r = 0; r < 4; r++) acc[n][r] *= alpha[r];
    }
    bf16x8 pf = *reinterpret_cast<const bf16x8*>(&Ps[wid][0] + l15 * 32 + l4 * 8);
#pragma unroll
    for (int n = 0; n < 32; n++) {
      const int row = n * 16 + l15;
      bf16x8 vb = *reinterpret_cast<const bf16x8*>(Vts + row * 32 + ((l4 * 8) ^ ((row & 3) << 3)));
      acc[n] = MFMA16(pf, vb, acc[n]);
    }
    __syncthreads();
  }

  __bf16* Osel = (SPLIT && ks) ? O1 : O0;
#pragma unroll
  for (int r = 0; r < 4; r++) {
    const int qg = qw + l4 * 4 + r;
    const float inv = 1.0f / lrow[r];
    __bf16* Og = Osel + ((size_t)(b * 2048 + qg) * (512 * G) + hl * 512);
#pragma unroll
    for (int n = 0; n < 32; n++) Og[n * 16 + l15] = (__bf16)(acc[n][r] * inv);
    if constexpr (SPLIT) {
      if (l15 == 0) Ml[ks * bhN * 2048 + bh * 2048 + qg] = make_float2(mrow[r], lrow[r]);
    }
  }
}

// ---------------- split-K merge: O0 = (w0*O0 + w1*O1) / (w0+w1) ----------------
__global__ void merge_k(__bf16* __restrict__ O0, const __bf16* __restrict__ O1,
                        const float2* __restrict__ Ml, int G, int lg, int n8) {
  int idx = blockIdx.x * 256 + threadIdx.x;
  if (idx >= n8) return;
  const int bhN = 4 * G;
  size_t flat = (size_t)idx * 8;
  int rowG = (int)(flat >> 9);      // / 512
  int hl = rowG & (G - 1);
  int bm = rowG >> lg;
  int b = bm >> 11, m = bm & 2047;
  int bh = b * G + hl;
  float2 ml0 = Ml[bh * 2048 + m];
  float2 ml1 = Ml[bhN * 2048 + bh * 2048 + m];
  float mm = fmaxf(ml0.x, ml1.x);
  float w0 = __expf(ml0.x - mm) * ml0.y;
  bool h1 = (ml1.y > 0.f);  // false for empty/NaN partials
  float w1 = h1 ? __expf(ml1.x - mm) * ml1.y : 0.f;
  float inv = 1.f / (w0 + w1);
  float a0 = w0 * inv, a1 = w1 * inv;
  bf16x8 v0 = *reinterpret_cast<const bf16x8*>(O0 + flat);
  bf16x8 out;
  if (h1) {
    bf16x8 v1 = *reinterpret_cast<const bf16x8*>(O1 + flat);
#pragma unroll
    for (int j = 0; j < 8; j++) out[j] = (__bf16)(a0 * (float)v0[j] + a1 * (float)v1[j]);
  } else {
#pragma unroll
    for (int j = 0; j < 8; j++) out[j] = (__bf16)(a0 * (float)v0[j]);
  }
  *reinterpret_cast<bf16x8*>(O0 + flat) = out;
}

// ---------------- output projection: 128x64 tile ----------------
__global__ __launch_bounds__(256) void out_gemm_k(
    const __bf16* __restrict__ A, const __bf16* __restrict__ Wo,
    const float* __restrict__ bias, float* __restrict__ Y, int G, int first) {
  const int AS = 512 * G;
  const int mbase = blockIdx.x * 128, nbase = blockIdx.y * 64;
  __shared__ alignas(16) __bf16 As[128 * 64];
  __shared__ alignas(16) __bf16 Bs[64 * 64];
  const int tid = threadIdx.x;
  const int lane = tid & 63, wid = tid >> 6;
  const int wr = wid >> 1, wc = wid & 1;
  const int l15 = lane & 15, l4 = lane >> 4;

  f32x4 acc[4][2];
#pragma unroll
  for (int i = 0; i < 4; i++)
#pragma unroll
    for (int j = 0; j < 2; j++) acc[i][j] = f32x4{0.f, 0.f, 0.f, 0.f};

  const int nkt = 8 * G;
  for (int kt = 0; kt < nkt; ++kt) {
    const int kb = kt * 64;
#pragma unroll
    for (int i = 0; i < 4; i++) {
      int chunk = i * 256 + tid;
      int row = chunk >> 3, col = (chunk & 7) * 8;
      g2l16(A + (size_t)(mbase + row) * AS + kb + col, As + (i * 256 + (tid & ~63)) * 8);
    }
#pragma unroll
    for (int i = 0; i < 2; i++) {
      int chunk = i * 256 + tid;
      int row = chunk >> 3, col = (chunk & 7) * 8;
      g2l16(Wo + (size_t)(nbase + row) * 4096 + kb + col, Bs + (i * 256 + (tid & ~63)) * 8);
    }
    __syncthreads();
#pragma unroll
    for (int kk = 0; kk < 2; ++kk) {
      bf16x8 a[4], b[2];
#pragma unroll
      for (int i = 0; i < 4; i++)
        a[i] = *reinterpret_cast<const bf16x8*>(As + (wr * 64 + i * 16 + l15) * 64 + kk * 32 + l4 * 8);
#pragma unroll
      for (int j = 0; j < 2; j++)
        b[j] = *reinterpret_cast<const bf16x8*>(Bs + (wc * 32 + j * 16 + l15) * 64 + kk * 32 + l4 * 8);
#pragma unroll
      for (int i = 0; i < 4; i++)
#pragma unroll
        for (int j = 0; j < 2; j++) acc[i][j] = MFMA16(a[i], b[j], acc[i][j]);
    }
    __syncthreads();
  }

#pragma unroll
  for (int i = 0; i < 4; i++) {
#pragma unroll
    for (int j = 0; j < 2; j++) {
      const int col = nbase + wc * 32 + j * 16 + l15;
#pragma unroll
      for (int r = 0; r < 4; r++) {
        const int row = mbase + wr * 64 + i * 16 + l4 * 4 + r;
        float prev = first ? bias[col] : Y[(size_t)row * 512 + col];
        Y[(size_t)row * 512 + col] = prev + acc[i][j][r];
      }
    }
  }
}

extern "C" void kernel_launch(void* const* d_in, const int* in_sizes, int n_in,
                              void* d_out, int out_size, void* d_ws, size_t ws_size,
                              hipStream_t stream) {
  (void)in_sizes; (void)n_in; (void)out_size;
  const float* x = (const float*)d_in[0];
  const float* wq = (const float*)d_in[1];
  const float* wk = (const float*)d_in[2];
  const float* wv = (const float*)d_in[3];
  const float* wo = (const float*)d_in[4];
  const float* bo = (const float*)d_in[5];
  float* y = (float*)d_out;

  char* base = (char*)d_ws;
  size_t off = 0;
  auto alloc = [&](size_t bytes) -> void* {
    void* p = base + off;
    off += (bytes + 255) & ~(size_t)255;
    return p;
  };
  __bf16* xb = (__bf16*)alloc((size_t)8192 * 512 * 2);
  __bf16* wqb = (__bf16*)alloc((size_t)8 * 512 * 512 * 2);
  __bf16* wkb = (__bf16*)alloc((size_t)8 * 512 * 512 * 2);
  __bf16* wvb = (__bf16*)alloc((size_t)8 * 512 * 512 * 2);
  __bf16* wob = (__bf16*)alloc((size_t)512 * 4096 * 2);
  float* ct = (float*)alloc((size_t)2048 * 256 * 4);
  float* st = (float*)alloc((size_t)2048 * 256 * 4);
  const size_t persist = off;

  int G = 0, lg = 0;
  for (int g = 8, l = 3; g >= 1; g >>= 1, --l) {
    size_t T = ((size_t)g * 4 * 2048 * 512 * 2 + 255) & ~(size_t)255;
    if (persist + 4 * T <= ws_size) { G = g; lg = l; break; }
  }
  if (G == 0) return;

  const int bhN = 4 * G;
  size_t T = ((size_t)G * 4 * 2048 * 512 * 2 + 255) & ~(size_t)255;
  size_t mlBytes = ((size_t)2 * bhN * 2048 * sizeof(float2) + 255) & ~(size_t)255;
  // split path needs an extra partial-O buffer + ml
  bool SPLIT = (G >= 2) && (persist + 5 * T + mlBytes <= ws_size);

  __bf16* Qb = (__bf16*)(base + persist);
  __bf16* Kb = (__bf16*)(base + persist + T);
  __bf16* VTb = (__bf16*)(base + persist + 2 * T);
  __bf16* Ob = (__bf16*)(base + persist + 3 * T);
  __bf16* O1b = SPLIT ? (__bf16*)(base + persist + 4 * T) : Ob;
  float2* Mlb = SPLIT ? (float2*)(base + persist + 5 * T) : (float2*)(base + persist);

  prep_k<<<14336, 256, 0, stream>>>(x, wq, wk, wv, wo, xb, wqb, wkb, wvb, wob, ct, st);

  const int n8 = bhN * 2048 * 64;  // bf16x8 chunks in one group's O
  for (int h0 = 0; h0 < 8; h0 += G) {
    qkv_gemm_k<<<dim3(64, 4, 3 * G), 256, 0, stream>>>(xb, wqb, wkb, wvb, ct, st,
                                                       Qb, Kb, VTb, G, lg, h0);
    if (SPLIT) {
      flash_attn_k<1><<<dim3(32 * bhN), 512, 0, stream>>>(Qb, Kb, VTb, Ob, O1b, Mlb, G, lg);
      merge_k<<<(n8 + 255) / 256, 256, 0, stream>>>(Ob, O1b, Mlb, G, lg, n8);
    } else {
      flash_attn_k<0><<<dim3(16, bhN), 512, 0, stream>>>(Qb, Kb, VTb, Ob, O1b, Mlb, G, lg);
    }
    out_gemm_k<<<dim3(64, 8), 256, 0, stream>>>(Ob, wob + h0 * 512, bo, y, G, h0 == 0);
  }
}

// Round 14
// 653.908 us; speedup vs baseline: 1.7501x; 1.0700x over previous
//
#include <hip/hip_runtime.h>
#include <hip/hip_bf16.h>
#include <math.h>

// B=4, M=2048, D=512, H=8. Heads in groups of G (G=4 on this harness).

typedef __attribute__((ext_vector_type(8))) __bf16 bf16x8;
typedef __attribute__((ext_vector_type(4))) __bf16 bf16x4;
typedef __attribute__((ext_vector_type(4))) float f32x4;

#define MFMA16(a, b, c) __builtin_amdgcn_mfma_f32_16x16x32_bf16((a), (b), (c), 0, 0, 0)

__device__ __forceinline__ void g2l16(const void* g, void* l) {
  __builtin_amdgcn_global_load_lds((const __attribute__((address_space(1))) void*)g,
                                   (__attribute__((address_space(3))) void*)l, 16, 0, 0);
}

// ---------------- fused prep: all fp32->bf16 casts + RoPE tables ----------------
__global__ void prep_k(const float* __restrict__ x, const float* __restrict__ wq,
                       const float* __restrict__ wk, const float* __restrict__ wv,
                       const float* __restrict__ wo,
                       __bf16* __restrict__ xb, __bf16* __restrict__ wqb,
                       __bf16* __restrict__ wkb, __bf16* __restrict__ wvb,
                       __bf16* __restrict__ wob,
                       float* __restrict__ ct, float* __restrict__ st) {
  int i = blockIdx.x * 256 + threadIdx.x;
  if (i < 3145728) {
    const float* src;
    __bf16* dst;
    int off = i;
    if (i < 1048576) { src = x; dst = xb; }
    else if (i < 1572864) { src = wq; dst = wqb; off = i - 1048576; }
    else if (i < 2097152) { src = wk; dst = wkb; off = i - 1572864; }
    else if (i < 2621440) { src = wv; dst = wvb; off = i - 2097152; }
    else { src = wo; dst = wob; off = i - 2621440; }
    float4 f = reinterpret_cast<const float4*>(src)[off];
    bf16x4 o;
    o.x = (__bf16)f.x; o.y = (__bf16)f.y; o.z = (__bf16)f.z; o.w = (__bf16)f.w;
    reinterpret_cast<bf16x4*>(dst)[off] = o;
  } else {
    int idx = i - 3145728;  // 2048*256
    int m = idx >> 8, j = idx & 255;
    float e = (-2.0f * ((float)j - 1.0f) / 512.0f) * 13.287712379549449f;  // log2(1e4)
    float theta = exp2f(e);
    float ang = (float)m * theta;
    float s, c;
    sincosf(ang, &s, &c);
    ct[idx] = c;
    st[idx] = s;
  }
}

// ---------------- QKV projection: z = which*G + hl; V written directly transposed ----------------
__global__ __launch_bounds__(256, 2) void qkv_gemm_k(
    const __bf16* __restrict__ Xb,
    const __bf16* __restrict__ Wqb, const __bf16* __restrict__ Wkb, const __bf16* __restrict__ Wvb,
    const float* __restrict__ ct, const float* __restrict__ st,
    __bf16* __restrict__ Q, __bf16* __restrict__ K, __bf16* __restrict__ VT,
    int G, int lg, int h0) {
  const int z = blockIdx.z;
  const int which = z >> lg, hl = z & (G - 1);
  const int h = h0 + hl;
  const __bf16* W = (which == 0 ? Wqb : which == 1 ? Wkb : Wvb) + (size_t)h * 262144;

  const int mbase = blockIdx.x * 128;
  const int nbase = blockIdx.y * 128;

  __shared__ alignas(16) __bf16 As[128 * 64];
  __shared__ alignas(16) __bf16 Bs[128 * 64];

  const int tid = threadIdx.x;
  const int lane = tid & 63, wid = tid >> 6;
  const int wr = wid >> 1, wc = wid & 1;
  const int l15 = lane & 15, l4 = lane >> 4;

  f32x4 acc[4][4];
#pragma unroll
  for (int i = 0; i < 4; i++)
#pragma unroll
    for (int j = 0; j < 4; j++) acc[i][j] = f32x4{0.f, 0.f, 0.f, 0.f};

  for (int kt = 0; kt < 8; ++kt) {
    const int kb = kt * 64;
#pragma unroll
    for (int i = 0; i < 4; i++) {
      int chunk = i * 256 + tid;
      int row = chunk >> 3, col = (chunk & 7) * 8;
      g2l16(Xb + (size_t)(mbase + row) * 512 + kb + col, As + (i * 256 + (tid & ~63)) * 8);
    }
#pragma unroll
    for (int i = 0; i < 4; i++) {
      int chunk = i * 256 + tid;
      int row = chunk >> 3, col = (chunk & 7) * 8;
      g2l16(W + (size_t)(nbase + row) * 512 + kb + col, Bs + (i * 256 + (tid & ~63)) * 8);
    }
    __syncthreads();
#pragma unroll
    for (int kk = 0; kk < 2; ++kk) {
      bf16x8 a[4], b[4];
#pragma unroll
      for (int i = 0; i < 4; i++)
        a[i] = *reinterpret_cast<const bf16x8*>(As + (wr * 64 + i * 16 + l15) * 64 + kk * 32 + l4 * 8);
#pragma unroll
      for (int j = 0; j < 4; j++)
        b[j] = *reinterpret_cast<const bf16x8*>(Bs + (wc * 64 + j * 16 + l15) * 64 + kk * 32 + l4 * 8);
#pragma unroll
      for (int i = 0; i < 4; i++)
#pragma unroll
        for (int j = 0; j < 4; j++) acc[i][j] = MFMA16(a[i], b[j], acc[i][j]);
    }
    __syncthreads();
  }

  if (which == 2) {
    const int b_ = mbase >> 11;
    const int mloc = mbase & 2047;
    __bf16* Tgw = VT + (size_t)(b_ * G + hl) * 512 * 2048;
#pragma unroll
    for (int i = 0; i < 4; i++) {
#pragma unroll
      for (int j = 0; j < 4; j++) {
        const int col = nbase + wc * 64 + j * 16 + l15;
        const int m0 = mloc + wr * 64 + i * 16 + l4 * 4;
        bf16x4 pk;
        pk.x = (__bf16)acc[i][j][0];
        pk.y = (__bf16)acc[i][j][1];
        pk.z = (__bf16)acc[i][j][2];
        pk.w = (__bf16)acc[i][j][3];
        *reinterpret_cast<bf16x4*>(&Tgw[(size_t)col * 2048 + m0]) = pk;
      }
    }
  } else {
    __bf16* Out = which ? K : Q;
#pragma unroll
    for (int i = 0; i < 4; i++) {
#pragma unroll
      for (int j = 0; j < 4; j++) {
        const int col = nbase + wc * 64 + j * 16 + l15;
#pragma unroll
        for (int r = 0; r < 4; r++) {
          const int rowg = mbase + wr * 64 + i * 16 + l4 * 4 + r;
          const int b_ = rowg >> 11, m = rowg & 2047;
          float v = acc[i][j][r];
          float pv = __shfl_xor(v, 1, 64);
          float c = ct[m * 256 + (col >> 1)];
          float s = st[m * 256 + (col >> 1)];
          v = (col & 1) ? (v * c - pv * s) : (v * c + pv * s);
          Out[(size_t)((b_ * G + hl) * 2048 + m) * 512 + col] = (__bf16)v;
        }
      }
    }
  }
}

// ---------------- causal flash attention (split-K, phase-uniform V swizzle, defer-max) ----------------
// SPLIT=1: 1-D grid 32*bhN; (q,ks=0) and (15-q,ks=1) share a CU -> 36 tiles/CU, 2 blocks/CU.
// V swizzle key (row>>1)&3: per-16-lane-phase start banks are uniform (2 lanes/bank) for the
// PV ds_read_b128 -> kills the 1.9e7 bank-conflict cycles the row&3 key caused.
template <int SPLIT>
__global__ __launch_bounds__(512) void flash_attn_k(
    const __bf16* __restrict__ Q, const __bf16* __restrict__ K, const __bf16* __restrict__ VT,
    __bf16* __restrict__ O0, __bf16* __restrict__ O1, float2* __restrict__ Ml,
    int G, int lg) {
  const int bhN = 4 * G;
  int bh, qblk, kt0, kt1, ks;
  if constexpr (SPLIT) {
    const int L = blockIdx.x;
    bh = L % bhN;
    const int s_ = L / bhN;  // 0..31
    ks = (s_ < 16) ? 0 : 1;
    qblk = ks ? (31 - s_) : s_;
    const int hn = 2 * qblk + 2;
    kt0 = ks * hn;
    kt1 = kt0 + hn;
  } else {
    const int L = blockIdx.x + 16 * blockIdx.y;
    const int half = L / (8 * bhN);
    const int r_ = L % (8 * bhN);
    bh = r_ % bhN;
    const int p_ = r_ / bhN;
    qblk = half ? (15 - p_) : p_;
    kt0 = 0;
    kt1 = 4 * qblk + 4;
    ks = 0;
  }
  const int b = bh >> lg, hl = bh & (G - 1);
  const int tid = threadIdx.x, lane = tid & 63, wid = tid >> 6;
  const int l15 = lane & 15, l4 = lane >> 4;
  const int qw = qblk * 128 + wid * 16;

  __shared__ alignas(16) __bf16 Ks[32 * 512];
  __shared__ alignas(16) __bf16 Vts[512 * 32];
  __shared__ alignas(16) __bf16 Ps[8][16 * 32];

  const __bf16* Qg = Q + ((size_t)bh * 2048 + qw) * 512;
  const __bf16* Kg = K + (size_t)bh * 2048 * 512;
  const __bf16* Tg = VT + (size_t)bh * 512 * 2048;

  bf16x8 qf[16];
#pragma unroll
  for (int c = 0; c < 16; c++)
    qf[c] = *reinterpret_cast<const bf16x8*>(Qg + l15 * 512 + c * 32 + l4 * 8);

  f32x4 acc[32];
#pragma unroll
  for (int n = 0; n < 32; n++) acc[n] = f32x4{0.f, 0.f, 0.f, 0.f};
  float mrow[4] = {-INFINITY, -INFINITY, -INFINITY, -INFINITY};
  float lrow[4] = {0.f, 0.f, 0.f, 0.f};

  const float scale = 0.04419417382415922f;  // 1/sqrt(512)

  for (int kt = kt0; kt < kt1; ++kt) {
    const int kb = kt * 32;
#pragma unroll
    for (int i = 0; i < 4; i++) {
      int chunk = i * 512 + tid;
      int row = chunk >> 6, c16 = chunk & 63;
      g2l16(Kg + (size_t)(kb + row) * 512 + ((c16 ^ (row & 7)) << 3),
            Ks + (i * 512 + (tid & ~63)) * 8);
    }
#pragma unroll
    for (int i = 0; i < 4; i++) {
      int chunk = i * 512 + tid;
      int row = chunk >> 2, c4 = chunk & 3;
      g2l16(Tg + (size_t)row * 2048 + kb + ((c4 ^ ((row >> 1) & 3)) << 3),
            Vts + (i * 512 + (tid & ~63)) * 8);
    }
    __syncthreads();

    f32x4 sv0 = f32x4{0.f, 0.f, 0.f, 0.f}, sv1 = f32x4{0.f, 0.f, 0.f, 0.f};
#pragma unroll
    for (int c = 0; c < 16; c++) {
      const int off = c * 32 + l4 * 8;
      const int r0 = l15, r1 = 16 + l15;
      bf16x8 b0 = *reinterpret_cast<const bf16x8*>(Ks + r0 * 512 + (off ^ ((r0 & 7) << 3)));
      bf16x8 b1 = *reinterpret_cast<const bf16x8*>(Ks + r1 * 512 + (off ^ ((r1 & 7) << 3)));
      sv0 = MFMA16(qf[c], b0, sv0);
      sv1 = MFMA16(qf[c], b1, sv1);
    }

    // online softmax with defer-max (THR=8)
    float mx[4];
#pragma unroll
    for (int r = 0; r < 4; r++) {
      const int qg = qw + l4 * 4 + r;
      float s0 = sv0[r] * scale;
      float s1 = sv1[r] * scale;
      if (kb + l15 > qg) s0 = -INFINITY;
      if (kb + 16 + l15 > qg) s1 = -INFINITY;
      sv0[r] = s0; sv1[r] = s1;
      float m_ = fmaxf(s0, s1);
      m_ = fmaxf(m_, __shfl_xor(m_, 1, 64));
      m_ = fmaxf(m_, __shfl_xor(m_, 2, 64));
      m_ = fmaxf(m_, __shfl_xor(m_, 4, 64));
      m_ = fmaxf(m_, __shfl_xor(m_, 8, 64));
      mx[r] = m_;
    }
    bool need = (mx[0] > mrow[0] + 8.f) || (mx[1] > mrow[1] + 8.f) ||
                (mx[2] > mrow[2] + 8.f) || (mx[3] > mrow[3] + 8.f);
    const bool doresc = __any(need);
    if (doresc) {
      float alpha[4];
#pragma unroll
      for (int r = 0; r < 4; r++) {
        float mn = fmaxf(mrow[r], mx[r]);
        alpha[r] = __expf(mrow[r] - mn);  // exact 1.0 when mx <= mrow
        lrow[r] *= alpha[r];
        mrow[r] = mn;
      }
#pragma unroll
      for (int n = 0; n < 32; n++) {
#pragma unroll
        for (int r = 0; r < 4; r++) acc[n][r] *= alpha[r];
      }
    }
#pragma unroll
    for (int r = 0; r < 4; r++) {
      float p0 = __expf(sv0[r] - mrow[r]);
      float p1 = __expf(sv1[r] - mrow[r]);
      float rs = p0 + p1;
      rs += __shfl_xor(rs, 1, 64);
      rs += __shfl_xor(rs, 2, 64);
      rs += __shfl_xor(rs, 4, 64);
      rs += __shfl_xor(rs, 8, 64);
      lrow[r] += rs;
      __bf16* P = &Ps[wid][0];
      P[(l4 * 4 + r) * 32 + l15] = (__bf16)p0;
      P[(l4 * 4 + r) * 32 + 16 + l15] = (__bf16)p1;
    }
    bf16x8 pf = *reinterpret_cast<const bf16x8*>(&Ps[wid][0] + l15 * 32 + l4 * 8);
#pragma unroll
    for (int n = 0; n < 32; n++) {
      const int row = n * 16 + l15;
      bf16x8 vb = *reinterpret_cast<const bf16x8*>(Vts + row * 32 + ((l4 * 8) ^ (((row >> 1) & 3) << 3)));
      acc[n] = MFMA16(pf, vb, acc[n]);
    }
    __syncthreads();
  }

  __bf16* Osel = (SPLIT && ks) ? O1 : O0;
#pragma unroll
  for (int r = 0; r < 4; r++) {
    const int qg = qw + l4 * 4 + r;
    const float inv = 1.0f / lrow[r];
    __bf16* Og = Osel + ((size_t)(b * 2048 + qg) * (512 * G) + hl * 512);
#pragma unroll
    for (int n = 0; n < 32; n++) Og[n * 16 + l15] = (__bf16)(acc[n][r] * inv);
    if constexpr (SPLIT) {
      if (l15 == 0) Ml[ks * bhN * 2048 + bh * 2048 + qg] = make_float2(mrow[r], lrow[r]);
    }
  }
}

// ---------------- split-K merge: O0 = (w0*O0 + w1*O1) / (w0+w1) ----------------
__global__ void merge_k(__bf16* __restrict__ O0, const __bf16* __restrict__ O1,
                        const float2* __restrict__ Ml, int G, int lg, int n8) {
  int idx = blockIdx.x * 256 + threadIdx.x;
  if (idx >= n8) return;
  const int bhN = 4 * G;
  size_t flat = (size_t)idx * 8;
  int rowG = (int)(flat >> 9);      // / 512
  int hl = rowG & (G - 1);
  int bm = rowG >> lg;
  int b = bm >> 11, m = bm & 2047;
  int bh = b * G + hl;
  float2 ml0 = Ml[bh * 2048 + m];
  float2 ml1 = Ml[bhN * 2048 + bh * 2048 + m];
  float mm = fmaxf(ml0.x, ml1.x);
  float w0 = __expf(ml0.x - mm) * ml0.y;
  bool h1 = (ml1.y > 0.f);  // false for empty/NaN partials
  float w1 = h1 ? __expf(ml1.x - mm) * ml1.y : 0.f;
  float inv = 1.f / (w0 + w1);
  float a0 = w0 * inv, a1 = w1 * inv;
  bf16x8 v0 = *reinterpret_cast<const bf16x8*>(O0 + flat);
  bf16x8 out;
  if (h1) {
    bf16x8 v1 = *reinterpret_cast<const bf16x8*>(O1 + flat);
#pragma unroll
    for (int j = 0; j < 8; j++) out[j] = (__bf16)(a0 * (float)v0[j] + a1 * (float)v1[j]);
  } else {
#pragma unroll
    for (int j = 0; j < 8; j++) out[j] = (__bf16)(a0 * (float)v0[j]);
  }
  *reinterpret_cast<bf16x8*>(O0 + flat) = out;
}

// ---------------- output projection: 128x64 tile ----------------
__global__ __launch_bounds__(256) void out_gemm_k(
    const __bf16* __restrict__ A, const __bf16* __restrict__ Wo,
    const float* __restrict__ bias, float* __restrict__ Y, int G, int first) {
  const int AS = 512 * G;
  const int mbase = blockIdx.x * 128, nbase = blockIdx.y * 64;
  __shared__ alignas(16) __bf16 As[128 * 64];
  __shared__ alignas(16) __bf16 Bs[64 * 64];
  const int tid = threadIdx.x;
  const int lane = tid & 63, wid = tid >> 6;
  const int wr = wid >> 1, wc = wid & 1;
  const int l15 = lane & 15, l4 = lane >> 4;

  f32x4 acc[4][2];
#pragma unroll
  for (int i = 0; i < 4; i++)
#pragma unroll
    for (int j = 0; j < 2; j++) acc[i][j] = f32x4{0.f, 0.f, 0.f, 0.f};

  const int nkt = 8 * G;
  for (int kt = 0; kt < nkt; ++kt) {
    const int kb = kt * 64;
#pragma unroll
    for (int i = 0; i < 4; i++) {
      int chunk = i * 256 + tid;
      int row = chunk >> 3, col = (chunk & 7) * 8;
      g2l16(A + (size_t)(mbase + row) * AS + kb + col, As + (i * 256 + (tid & ~63)) * 8);
    }
#pragma unroll
    for (int i = 0; i < 2; i++) {
      int chunk = i * 256 + tid;
      int row = chunk >> 3, col = (chunk & 7) * 8;
      g2l16(Wo + (size_t)(nbase + row) * 4096 + kb + col, Bs + (i * 256 + (tid & ~63)) * 8);
    }
    __syncthreads();
#pragma unroll
    for (int kk = 0; kk < 2; ++kk) {
      bf16x8 a[4], b[2];
#pragma unroll
      for (int i = 0; i < 4; i++)
        a[i] = *reinterpret_cast<const bf16x8*>(As + (wr * 64 + i * 16 + l15) * 64 + kk * 32 + l4 * 8);
#pragma unroll
      for (int j = 0; j < 2; j++)
        b[j] = *reinterpret_cast<const bf16x8*>(Bs + (wc * 32 + j * 16 + l15) * 64 + kk * 32 + l4 * 8);
#pragma unroll
      for (int i = 0; i < 4; i++)
#pragma unroll
        for (int j = 0; j < 2; j++) acc[i][j] = MFMA16(a[i], b[j], acc[i][j]);
    }
    __syncthreads();
  }

#pragma unroll
  for (int i = 0; i < 4; i++) {
#pragma unroll
    for (int j = 0; j < 2; j++) {
      const int col = nbase + wc * 32 + j * 16 + l15;
#pragma unroll
      for (int r = 0; r < 4; r++) {
        const int row = mbase + wr * 64 + i * 16 + l4 * 4 + r;
        float prev = first ? bias[col] : Y[(size_t)row * 512 + col];
        Y[(size_t)row * 512 + col] = prev + acc[i][j][r];
      }
    }
  }
}

extern "C" void kernel_launch(void* const* d_in, const int* in_sizes, int n_in,
                              void* d_out, int out_size, void* d_ws, size_t ws_size,
                              hipStream_t stream) {
  (void)in_sizes; (void)n_in; (void)out_size;
  const float* x = (const float*)d_in[0];
  const float* wq = (const float*)d_in[1];
  const float* wk = (const float*)d_in[2];
  const float* wv = (const float*)d_in[3];
  const float* wo = (const float*)d_in[4];
  const float* bo = (const float*)d_in[5];
  float* y = (float*)d_out;

  char* base = (char*)d_ws;
  size_t off = 0;
  auto alloc = [&](size_t bytes) -> void* {
    void* p = base + off;
    off += (bytes + 255) & ~(size_t)255;
    return p;
  };
  __bf16* xb = (__bf16*)alloc((size_t)8192 * 512 * 2);
  __bf16* wqb = (__bf16*)alloc((size_t)8 * 512 * 512 * 2);
  __bf16* wkb = (__bf16*)alloc((size_t)8 * 512 * 512 * 2);
  __bf16* wvb = (__bf16*)alloc((size_t)8 * 512 * 512 * 2);
  __bf16* wob = (__bf16*)alloc((size_t)512 * 4096 * 2);
  float* ct = (float*)alloc((size_t)2048 * 256 * 4);
  float* st = (float*)alloc((size_t)2048 * 256 * 4);
  const size_t persist = off;

  int G = 0, lg = 0;
  for (int g = 8, l = 3; g >= 1; g >>= 1, --l) {
    size_t T = ((size_t)g * 4 * 2048 * 512 * 2 + 255) & ~(size_t)255;
    if (persist + 4 * T <= ws_size) { G = g; lg = l; break; }
  }
  if (G == 0) return;

  const int bhN = 4 * G;
  size_t T = ((size_t)G * 4 * 2048 * 512 * 2 + 255) & ~(size_t)255;
  size_t mlBytes = ((size_t)2 * bhN * 2048 * sizeof(float2) + 255) & ~(size_t)255;
  bool SPLIT = (G >= 2) && (persist + 5 * T + mlBytes <= ws_size);

  __bf16* Qb = (__bf16*)(base + persist);
  __bf16* Kb = (__bf16*)(base + persist + T);
  __bf16* VTb = (__bf16*)(base + persist + 2 * T);
  __bf16* Ob = (__bf16*)(base + persist + 3 * T);
  __bf16* O1b = SPLIT ? (__bf16*)(base + persist + 4 * T) : Ob;
  float2* Mlb = SPLIT ? (float2*)(base + persist + 5 * T) : (float2*)(base + persist);

  prep_k<<<14336, 256, 0, stream>>>(x, wq, wk, wv, wo, xb, wqb, wkb, wvb, wob, ct, st);

  const int n8 = bhN * 2048 * 64;  // bf16x8 chunks in one group's O
  for (int h0 = 0; h0 < 8; h0 += G) {
    qkv_gemm_k<<<dim3(64, 4, 3 * G), 256, 0, stream>>>(xb, wqb, wkb, wvb, ct, st,
                                                       Qb, Kb, VTb, G, lg, h0);
    if (SPLIT) {
      flash_attn_k<1><<<dim3(32 * bhN), 512, 0, stream>>>(Qb, Kb, VTb, Ob, O1b, Mlb, G, lg);
      merge_k<<<(n8 + 255) / 256, 256, 0, stream>>>(Ob, O1b, Mlb, G, lg, n8);
    } else {
      flash_attn_k<0><<<dim3(16, bhN), 512, 0, stream>>>(Qb, Kb, VTb, Ob, O1b, Mlb, G, lg);
    }
    out_gemm_k<<<dim3(64, 8), 256, 0, stream>>>(Ob, wob + h0 * 512, bo, y, G, h0 == 0);
  }
}

// Round 15
// 642.856 us; speedup vs baseline: 1.7802x; 1.0172x over previous
//
#include <hip/hip_runtime.h>
#include <hip/hip_bf16.h>
#include <math.h>

// B=4, M=2048, D=512, H=8. Heads in groups of G (G=4 on this harness).

typedef __attribute__((ext_vector_type(8))) __bf16 bf16x8;
typedef __attribute__((ext_vector_type(4))) __bf16 bf16x4;
typedef __attribute__((ext_vector_type(4))) float f32x4;

#define MFMA16(a, b, c) __builtin_amdgcn_mfma_f32_16x16x32_bf16((a), (b), (c), 0, 0, 0)

__device__ __forceinline__ void g2l16(const void* g, void* l) {
  __builtin_amdgcn_global_load_lds((const __attribute__((address_space(1))) void*)g,
                                   (__attribute__((address_space(3))) void*)l, 16, 0, 0);
}

// ---------------- fused prep: all fp32->bf16 casts + RoPE tables ----------------
__global__ void prep_k(const float* __restrict__ x, const float* __restrict__ wq,
                       const float* __restrict__ wk, const float* __restrict__ wv,
                       const float* __restrict__ wo,
                       __bf16* __restrict__ xb, __bf16* __restrict__ wqb,
                       __bf16* __restrict__ wkb, __bf16* __restrict__ wvb,
                       __bf16* __restrict__ wob,
                       float* __restrict__ ct, float* __restrict__ st) {
  int i = blockIdx.x * 256 + threadIdx.x;
  if (i < 3145728) {
    const float* src;
    __bf16* dst;
    int off = i;
    if (i < 1048576) { src = x; dst = xb; }
    else if (i < 1572864) { src = wq; dst = wqb; off = i - 1048576; }
    else if (i < 2097152) { src = wk; dst = wkb; off = i - 1572864; }
    else if (i < 2621440) { src = wv; dst = wvb; off = i - 2097152; }
    else { src = wo; dst = wob; off = i - 2621440; }
    float4 f = reinterpret_cast<const float4*>(src)[off];
    bf16x4 o;
    o.x = (__bf16)f.x; o.y = (__bf16)f.y; o.z = (__bf16)f.z; o.w = (__bf16)f.w;
    reinterpret_cast<bf16x4*>(dst)[off] = o;
  } else {
    int idx = i - 3145728;  // 2048*256
    int m = idx >> 8, j = idx & 255;
    float e = (-2.0f * ((float)j - 1.0f) / 512.0f) * 13.287712379549449f;  // log2(1e4)
    float theta = exp2f(e);
    float ang = (float)m * theta;
    float s, c;
    sincosf(ang, &s, &c);
    ct[idx] = c;
    st[idx] = s;
  }
}

// ---------------- QKV projection: z = which*G + hl; V written directly transposed ----------------
__global__ __launch_bounds__(256, 2) void qkv_gemm_k(
    const __bf16* __restrict__ Xb,
    const __bf16* __restrict__ Wqb, const __bf16* __restrict__ Wkb, const __bf16* __restrict__ Wvb,
    const float* __restrict__ ct, const float* __restrict__ st,
    __bf16* __restrict__ Q, __bf16* __restrict__ K, __bf16* __restrict__ VT,
    int G, int lg, int h0) {
  const int z = blockIdx.z;
  const int which = z >> lg, hl = z & (G - 1);
  const int h = h0 + hl;
  const __bf16* W = (which == 0 ? Wqb : which == 1 ? Wkb : Wvb) + (size_t)h * 262144;

  const int mbase = blockIdx.x * 128;
  const int nbase = blockIdx.y * 128;

  __shared__ alignas(16) __bf16 As[128 * 64];
  __shared__ alignas(16) __bf16 Bs[128 * 64];

  const int tid = threadIdx.x;
  const int lane = tid & 63, wid = tid >> 6;
  const int wr = wid >> 1, wc = wid & 1;
  const int l15 = lane & 15, l4 = lane >> 4;

  f32x4 acc[4][4];
#pragma unroll
  for (int i = 0; i < 4; i++)
#pragma unroll
    for (int j = 0; j < 4; j++) acc[i][j] = f32x4{0.f, 0.f, 0.f, 0.f};

  for (int kt = 0; kt < 8; ++kt) {
    const int kb = kt * 64;
#pragma unroll
    for (int i = 0; i < 4; i++) {
      int chunk = i * 256 + tid;
      int row = chunk >> 3, col = (chunk & 7) * 8;
      g2l16(Xb + (size_t)(mbase + row) * 512 + kb + col, As + (i * 256 + (tid & ~63)) * 8);
    }
#pragma unroll
    for (int i = 0; i < 4; i++) {
      int chunk = i * 256 + tid;
      int row = chunk >> 3, col = (chunk & 7) * 8;
      g2l16(W + (size_t)(nbase + row) * 512 + kb + col, Bs + (i * 256 + (tid & ~63)) * 8);
    }
    __syncthreads();
#pragma unroll
    for (int kk = 0; kk < 2; ++kk) {
      bf16x8 a[4], b[4];
#pragma unroll
      for (int i = 0; i < 4; i++)
        a[i] = *reinterpret_cast<const bf16x8*>(As + (wr * 64 + i * 16 + l15) * 64 + kk * 32 + l4 * 8);
#pragma unroll
      for (int j = 0; j < 4; j++)
        b[j] = *reinterpret_cast<const bf16x8*>(Bs + (wc * 64 + j * 16 + l15) * 64 + kk * 32 + l4 * 8);
#pragma unroll
      for (int i = 0; i < 4; i++)
#pragma unroll
        for (int j = 0; j < 4; j++) acc[i][j] = MFMA16(a[i], b[j], acc[i][j]);
    }
    __syncthreads();
  }

  if (which == 2) {
    const int b_ = mbase >> 11;
    const int mloc = mbase & 2047;
    __bf16* Tgw = VT + (size_t)(b_ * G + hl) * 512 * 2048;
#pragma unroll
    for (int i = 0; i < 4; i++) {
#pragma unroll
      for (int j = 0; j < 4; j++) {
        const int col = nbase + wc * 64 + j * 16 + l15;
        const int m0 = mloc + wr * 64 + i * 16 + l4 * 4;
        bf16x4 pk;
        pk.x = (__bf16)acc[i][j][0];
        pk.y = (__bf16)acc[i][j][1];
        pk.z = (__bf16)acc[i][j][2];
        pk.w = (__bf16)acc[i][j][3];
        *reinterpret_cast<bf16x4*>(&Tgw[(size_t)col * 2048 + m0]) = pk;
      }
    }
  } else {
    __bf16* Out = which ? K : Q;
#pragma unroll
    for (int i = 0; i < 4; i++) {
#pragma unroll
      for (int j = 0; j < 4; j++) {
        const int col = nbase + wc * 64 + j * 16 + l15;
#pragma unroll
        for (int r = 0; r < 4; r++) {
          const int rowg = mbase + wr * 64 + i * 16 + l4 * 4 + r;
          const int b_ = rowg >> 11, m = rowg & 2047;
          float v = acc[i][j][r];
          float pv = __shfl_xor(v, 1, 64);
          float c = ct[m * 256 + (col >> 1)];
          float s = st[m * 256 + (col >> 1)];
          v = (col & 1) ? (v * c - pv * s) : (v * c + pv * s);
          Out[(size_t)((b_ * G + hl) * 2048 + m) * 512 + col] = (__bf16)v;
        }
      }
    }
  }
}

// ======== shared flash math (macro-free duplication kept minimal) ========
// flashA: proven R14 single-barrier schedule. flashB: 2-barrier drain-covered schedule.

template <int SPLIT>
__global__ __launch_bounds__(512) void flash_attn_k(
    const __bf16* __restrict__ Q, const __bf16* __restrict__ K, const __bf16* __restrict__ VT,
    __bf16* __restrict__ O0, __bf16* __restrict__ O1, float2* __restrict__ Ml,
    int G, int lg) {
  const int bhN = 4 * G;
  int bh, qblk, kt0, kt1, ks;
  if constexpr (SPLIT) {
    const int L = blockIdx.x;
    bh = L % bhN;
    const int s_ = L / bhN;  // 0..31
    ks = (s_ < 16) ? 0 : 1;
    qblk = ks ? (31 - s_) : s_;
    const int hn = 2 * qblk + 2;
    kt0 = ks * hn;
    kt1 = kt0 + hn;
  } else {
    const int L = blockIdx.x + 16 * blockIdx.y;
    const int half = L / (8 * bhN);
    const int r_ = L % (8 * bhN);
    bh = r_ % bhN;
    const int p_ = r_ / bhN;
    qblk = half ? (15 - p_) : p_;
    kt0 = 0;
    kt1 = 4 * qblk + 4;
    ks = 0;
  }
  const int b = bh >> lg, hl = bh & (G - 1);
  const int tid = threadIdx.x, lane = tid & 63, wid = tid >> 6;
  const int l15 = lane & 15, l4 = lane >> 4;
  const int qw = qblk * 128 + wid * 16;

  __shared__ alignas(16) __bf16 Ks[32 * 512];
  __shared__ alignas(16) __bf16 Vts[512 * 32];
  __shared__ alignas(16) __bf16 Ps[8][16 * 32];

  const __bf16* Qg = Q + ((size_t)bh * 2048 + qw) * 512;
  const __bf16* Kg = K + (size_t)bh * 2048 * 512;
  const __bf16* Tg = VT + (size_t)bh * 512 * 2048;

  bf16x8 qf[16];
#pragma unroll
  for (int c = 0; c < 16; c++)
    qf[c] = *reinterpret_cast<const bf16x8*>(Qg + l15 * 512 + c * 32 + l4 * 8);

  f32x4 acc[32];
#pragma unroll
  for (int n = 0; n < 32; n++) acc[n] = f32x4{0.f, 0.f, 0.f, 0.f};
  float mrow[4] = {-INFINITY, -INFINITY, -INFINITY, -INFINITY};
  float lrow[4] = {0.f, 0.f, 0.f, 0.f};

  const float scale = 0.04419417382415922f;  // 1/sqrt(512)

  for (int kt = kt0; kt < kt1; ++kt) {
    const int kb = kt * 32;
#pragma unroll
    for (int i = 0; i < 4; i++) {
      int chunk = i * 512 + tid;
      int row = chunk >> 6, c16 = chunk & 63;
      g2l16(Kg + (size_t)(kb + row) * 512 + ((c16 ^ (row & 7)) << 3),
            Ks + (i * 512 + (tid & ~63)) * 8);
    }
#pragma unroll
    for (int i = 0; i < 4; i++) {
      int chunk = i * 512 + tid;
      int row = chunk >> 2, c4 = chunk & 3;
      g2l16(Tg + (size_t)row * 2048 + kb + ((c4 ^ ((row >> 1) & 3)) << 3),
            Vts + (i * 512 + (tid & ~63)) * 8);
    }
    __syncthreads();

    f32x4 sv0 = f32x4{0.f, 0.f, 0.f, 0.f}, sv1 = f32x4{0.f, 0.f, 0.f, 0.f};
#pragma unroll
    for (int c = 0; c < 16; c++) {
      const int off = c * 32 + l4 * 8;
      const int r0 = l15, r1 = 16 + l15;
      bf16x8 b0 = *reinterpret_cast<const bf16x8*>(Ks + r0 * 512 + (off ^ ((r0 & 7) << 3)));
      bf16x8 b1 = *reinterpret_cast<const bf16x8*>(Ks + r1 * 512 + (off ^ ((r1 & 7) << 3)));
      sv0 = MFMA16(qf[c], b0, sv0);
      sv1 = MFMA16(qf[c], b1, sv1);
    }

    float mx[4];
#pragma unroll
    for (int r = 0; r < 4; r++) {
      const int qg = qw + l4 * 4 + r;
      float s0 = sv0[r] * scale;
      float s1 = sv1[r] * scale;
      if (kb + l15 > qg) s0 = -INFINITY;
      if (kb + 16 + l15 > qg) s1 = -INFINITY;
      sv0[r] = s0; sv1[r] = s1;
      float m_ = fmaxf(s0, s1);
      m_ = fmaxf(m_, __shfl_xor(m_, 1, 64));
      m_ = fmaxf(m_, __shfl_xor(m_, 2, 64));
      m_ = fmaxf(m_, __shfl_xor(m_, 4, 64));
      m_ = fmaxf(m_, __shfl_xor(m_, 8, 64));
      mx[r] = m_;
    }
    bool need = (mx[0] > mrow[0] + 8.f) || (mx[1] > mrow[1] + 8.f) ||
                (mx[2] > mrow[2] + 8.f) || (mx[3] > mrow[3] + 8.f);
    if (__any(need)) {
      float alpha[4];
#pragma unroll
      for (int r = 0; r < 4; r++) {
        float mn = fmaxf(mrow[r], mx[r]);
        alpha[r] = __expf(mrow[r] - mn);
        lrow[r] *= alpha[r];
        mrow[r] = mn;
      }
#pragma unroll
      for (int n = 0; n < 32; n++) {
#pragma unroll
        for (int r = 0; r < 4; r++) acc[n][r] *= alpha[r];
      }
    }
#pragma unroll
    for (int r = 0; r < 4; r++) {
      float p0 = __expf(sv0[r] - mrow[r]);
      float p1 = __expf(sv1[r] - mrow[r]);
      float rs = p0 + p1;
      rs += __shfl_xor(rs, 1, 64);
      rs += __shfl_xor(rs, 2, 64);
      rs += __shfl_xor(rs, 4, 64);
      rs += __shfl_xor(rs, 8, 64);
      lrow[r] += rs;
      __bf16* P = &Ps[wid][0];
      P[(l4 * 4 + r) * 32 + l15] = (__bf16)p0;
      P[(l4 * 4 + r) * 32 + 16 + l15] = (__bf16)p1;
    }
    bf16x8 pf = *reinterpret_cast<const bf16x8*>(&Ps[wid][0] + l15 * 32 + l4 * 8);
#pragma unroll
    for (int n = 0; n < 32; n++) {
      const int row = n * 16 + l15;
      bf16x8 vb = *reinterpret_cast<const bf16x8*>(Vts + row * 32 + ((l4 * 8) ^ (((row >> 1) & 3) << 3)));
      acc[n] = MFMA16(pf, vb, acc[n]);
    }
    __syncthreads();
  }

  __bf16* Osel = (SPLIT && ks) ? O1 : O0;
#pragma unroll
  for (int r = 0; r < 4; r++) {
    const int qg = qw + l4 * 4 + r;
    const float inv = 1.0f / lrow[r];
    __bf16* Og = Osel + ((size_t)(b * 2048 + qg) * (512 * G) + hl * 512);
#pragma unroll
    for (int n = 0; n < 32; n++) Og[n * 16 + l15] = (__bf16)(acc[n][r] * inv);
    if constexpr (SPLIT) {
      if (l15 == 0) Ml[ks * bhN * 2048 + bh * 2048 + qg] = make_float2(mrow[r], lrow[r]);
    }
  }
}

// ---------------- flashB: 2-barrier drain-covered schedule (A/B experiment) ----------------
// barrier1 drains K(kt) (covered by prev PV); V(kt) issued under QK+softmax; barrier2
// drains V(kt); K(kt+1) issued under PV. Same buffers/swizzles/numerics as flashA.
__global__ __launch_bounds__(512) void flashB_k(
    const __bf16* __restrict__ Q, const __bf16* __restrict__ K, const __bf16* __restrict__ VT,
    __bf16* __restrict__ O0, __bf16* __restrict__ O1, float2* __restrict__ Ml,
    int G, int lg) {
  const int bhN = 4 * G;
  const int L = blockIdx.x;
  const int bh = L % bhN;
  const int s_ = L / bhN;  // 0..31
  const int ks = (s_ < 16) ? 0 : 1;
  const int qblk = ks ? (31 - s_) : s_;
  const int hn = 2 * qblk + 2;
  const int kt0 = ks * hn, kt1 = kt0 + hn;
  const int b = bh >> lg, hl = bh & (G - 1);
  const int tid = threadIdx.x, lane = tid & 63, wid = tid >> 6;
  const int l15 = lane & 15, l4 = lane >> 4;
  const int qw = qblk * 128 + wid * 16;

  __shared__ alignas(16) __bf16 Ks[32 * 512];
  __shared__ alignas(16) __bf16 Vts[512 * 32];
  __shared__ alignas(16) __bf16 Ps[8][16 * 32];

  const __bf16* Qg = Q + ((size_t)bh * 2048 + qw) * 512;
  const __bf16* Kg = K + (size_t)bh * 2048 * 512;
  const __bf16* Tg = VT + (size_t)bh * 512 * 2048;

  bf16x8 qf[16];
#pragma unroll
  for (int c = 0; c < 16; c++)
    qf[c] = *reinterpret_cast<const bf16x8*>(Qg + l15 * 512 + c * 32 + l4 * 8);

  f32x4 acc[32];
#pragma unroll
  for (int n = 0; n < 32; n++) acc[n] = f32x4{0.f, 0.f, 0.f, 0.f};
  float mrow[4] = {-INFINITY, -INFINITY, -INFINITY, -INFINITY};
  float lrow[4] = {0.f, 0.f, 0.f, 0.f};

  const float scale = 0.04419417382415922f;

  auto stageK = [&](int kt2) {
#pragma unroll
    for (int i = 0; i < 4; i++) {
      int chunk = i * 512 + tid;
      int row = chunk >> 6, c16 = chunk & 63;
      g2l16(Kg + (size_t)(kt2 * 32 + row) * 512 + ((c16 ^ (row & 7)) << 3),
            Ks + (i * 512 + (tid & ~63)) * 8);
    }
  };
  auto stageV = [&](int kt2) {
#pragma unroll
    for (int i = 0; i < 4; i++) {
      int chunk = i * 512 + tid;
      int row = chunk >> 2, c4 = chunk & 3;
      g2l16(Tg + (size_t)row * 2048 + kt2 * 32 + ((c4 ^ ((row >> 1) & 3)) << 3),
            Vts + (i * 512 + (tid & ~63)) * 8);
    }
  };

  stageK(kt0);

  for (int kt = kt0; kt < kt1; ++kt) {
    const int kb = kt * 32;
    __syncthreads();  // barrier1: PV(kt-1) done everywhere; drains K(kt) (covered by prev PV)
    stageV(kt);       // flies under QK + softmax

    f32x4 sv0 = f32x4{0.f, 0.f, 0.f, 0.f}, sv1 = f32x4{0.f, 0.f, 0.f, 0.f};
#pragma unroll
    for (int c = 0; c < 16; c++) {
      const int off = c * 32 + l4 * 8;
      const int r0 = l15, r1 = 16 + l15;
      bf16x8 b0 = *reinterpret_cast<const bf16x8*>(Ks + r0 * 512 + (off ^ ((r0 & 7) << 3)));
      bf16x8 b1 = *reinterpret_cast<const bf16x8*>(Ks + r1 * 512 + (off ^ ((r1 & 7) << 3)));
      sv0 = MFMA16(qf[c], b0, sv0);
      sv1 = MFMA16(qf[c], b1, sv1);
    }

    float mx[4];
#pragma unroll
    for (int r = 0; r < 4; r++) {
      const int qg = qw + l4 * 4 + r;
      float s0 = sv0[r] * scale;
      float s1 = sv1[r] * scale;
      if (kb + l15 > qg) s0 = -INFINITY;
      if (kb + 16 + l15 > qg) s1 = -INFINITY;
      sv0[r] = s0; sv1[r] = s1;
      float m_ = fmaxf(s0, s1);
      m_ = fmaxf(m_, __shfl_xor(m_, 1, 64));
      m_ = fmaxf(m_, __shfl_xor(m_, 2, 64));
      m_ = fmaxf(m_, __shfl_xor(m_, 4, 64));
      m_ = fmaxf(m_, __shfl_xor(m_, 8, 64));
      mx[r] = m_;
    }
    bool need = (mx[0] > mrow[0] + 8.f) || (mx[1] > mrow[1] + 8.f) ||
                (mx[2] > mrow[2] + 8.f) || (mx[3] > mrow[3] + 8.f);
    if (__any(need)) {
      float alpha[4];
#pragma unroll
      for (int r = 0; r < 4; r++) {
        float mn = fmaxf(mrow[r], mx[r]);
        alpha[r] = __expf(mrow[r] - mn);
        lrow[r] *= alpha[r];
        mrow[r] = mn;
      }
#pragma unroll
      for (int n = 0; n < 32; n++) {
#pragma unroll
        for (int r = 0; r < 4; r++) acc[n][r] *= alpha[r];
      }
    }
#pragma unroll
    for (int r = 0; r < 4; r++) {
      float p0 = __expf(sv0[r] - mrow[r]);
      float p1 = __expf(sv1[r] - mrow[r]);
      float rs = p0 + p1;
      rs += __shfl_xor(rs, 1, 64);
      rs += __shfl_xor(rs, 2, 64);
      rs += __shfl_xor(rs, 4, 64);
      rs += __shfl_xor(rs, 8, 64);
      lrow[r] += rs;
      __bf16* P = &Ps[wid][0];
      P[(l4 * 4 + r) * 32 + l15] = (__bf16)p0;
      P[(l4 * 4 + r) * 32 + 16 + l15] = (__bf16)p1;
    }

    __syncthreads();                      // barrier2: drains V(kt); all waves done with Ks
    if (kt + 1 < kt1) stageK(kt + 1);     // flies under PV

    bf16x8 pf = *reinterpret_cast<const bf16x8*>(&Ps[wid][0] + l15 * 32 + l4 * 8);
#pragma unroll
    for (int n = 0; n < 32; n++) {
      const int row = n * 16 + l15;
      bf16x8 vb = *reinterpret_cast<const bf16x8*>(Vts + row * 32 + ((l4 * 8) ^ (((row >> 1) & 3) << 3)));
      acc[n] = MFMA16(pf, vb, acc[n]);
    }
  }

  __bf16* Osel = ks ? O1 : O0;
#pragma unroll
  for (int r = 0; r < 4; r++) {
    const int qg = qw + l4 * 4 + r;
    const float inv = 1.0f / lrow[r];
    __bf16* Og = Osel + ((size_t)(b * 2048 + qg) * (512 * G) + hl * 512);
#pragma unroll
    for (int n = 0; n < 32; n++) Og[n * 16 + l15] = (__bf16)(acc[n][r] * inv);
    if (l15 == 0) Ml[ks * bhN * 2048 + bh * 2048 + qg] = make_float2(mrow[r], lrow[r]);
  }
}

// ---------------- split-K merge ----------------
__global__ void merge_k(__bf16* __restrict__ O0, const __bf16* __restrict__ O1,
                        const float2* __restrict__ Ml, int G, int lg, int n8) {
  int idx = blockIdx.x * 256 + threadIdx.x;
  if (idx >= n8) return;
  const int bhN = 4 * G;
  size_t flat = (size_t)idx * 8;
  int rowG = (int)(flat >> 9);
  int hl = rowG & (G - 1);
  int bm = rowG >> lg;
  int b = bm >> 11, m = bm & 2047;
  int bh = b * G + hl;
  float2 ml0 = Ml[bh * 2048 + m];
  float2 ml1 = Ml[bhN * 2048 + bh * 2048 + m];
  float mm = fmaxf(ml0.x, ml1.x);
  float w0 = __expf(ml0.x - mm) * ml0.y;
  bool h1 = (ml1.y > 0.f);
  float w1 = h1 ? __expf(ml1.x - mm) * ml1.y : 0.f;
  float inv = 1.f / (w0 + w1);
  float a0 = w0 * inv, a1 = w1 * inv;
  bf16x8 v0 = *reinterpret_cast<const bf16x8*>(O0 + flat);
  bf16x8 out;
  if (h1) {
    bf16x8 v1 = *reinterpret_cast<const bf16x8*>(O1 + flat);
#pragma unroll
    for (int j = 0; j < 8; j++) out[j] = (__bf16)(a0 * (float)v0[j] + a1 * (float)v1[j]);
  } else {
#pragma unroll
    for (int j = 0; j < 8; j++) out[j] = (__bf16)(a0 * (float)v0[j]);
  }
  *reinterpret_cast<bf16x8*>(O0 + flat) = out;
}

// ---------------- output projection: 128x64 tile ----------------
__global__ __launch_bounds__(256) void out_gemm_k(
    const __bf16* __restrict__ A, const __bf16* __restrict__ Wo,
    const float* __restrict__ bias, float* __restrict__ Y, int G, int first) {
  const int AS = 512 * G;
  const int mbase = blockIdx.x * 128, nbase = blockIdx.y * 64;
  __shared__ alignas(16) __bf16 As[128 * 64];
  __shared__ alignas(16) __bf16 Bs[64 * 64];
  const int tid = threadIdx.x;
  const int lane = tid & 63, wid = tid >> 6;
  const int wr = wid >> 1, wc = wid & 1;
  const int l15 = lane & 15, l4 = lane >> 4;

  f32x4 acc[4][2];
#pragma unroll
  for (int i = 0; i < 4; i++)
#pragma unroll
    for (int j = 0; j < 2; j++) acc[i][j] = f32x4{0.f, 0.f, 0.f, 0.f};

  const int nkt = 8 * G;
  for (int kt = 0; kt < nkt; ++kt) {
    const int kb = kt * 64;
#pragma unroll
    for (int i = 0; i < 4; i++) {
      int chunk = i * 256 + tid;
      int row = chunk >> 3, col = (chunk & 7) * 8;
      g2l16(A + (size_t)(mbase + row) * AS + kb + col, As + (i * 256 + (tid & ~63)) * 8);
    }
#pragma unroll
    for (int i = 0; i < 2; i++) {
      int chunk = i * 256 + tid;
      int row = chunk >> 3, col = (chunk & 7) * 8;
      g2l16(Wo + (size_t)(nbase + row) * 4096 + kb + col, Bs + (i * 256 + (tid & ~63)) * 8);
    }
    __syncthreads();
#pragma unroll
    for (int kk = 0; kk < 2; ++kk) {
      bf16x8 a[4], b[2];
#pragma unroll
      for (int i = 0; i < 4; i++)
        a[i] = *reinterpret_cast<const bf16x8*>(As + (wr * 64 + i * 16 + l15) * 64 + kk * 32 + l4 * 8);
#pragma unroll
      for (int j = 0; j < 2; j++)
        b[j] = *reinterpret_cast<const bf16x8*>(Bs + (wc * 32 + j * 16 + l15) * 64 + kk * 32 + l4 * 8);
#pragma unroll
      for (int i = 0; i < 4; i++)
#pragma unroll
        for (int j = 0; j < 2; j++) acc[i][j] = MFMA16(a[i], b[j], acc[i][j]);
    }
    __syncthreads();
  }

#pragma unroll
  for (int i = 0; i < 4; i++) {
#pragma unroll
    for (int j = 0; j < 2; j++) {
      const int col = nbase + wc * 32 + j * 16 + l15;
#pragma unroll
      for (int r = 0; r < 4; r++) {
        const int row = mbase + wr * 64 + i * 16 + l4 * 4 + r;
        float prev = first ? bias[col] : Y[(size_t)row * 512 + col];
        Y[(size_t)row * 512 + col] = prev + acc[i][j][r];
      }
    }
  }
}

extern "C" void kernel_launch(void* const* d_in, const int* in_sizes, int n_in,
                              void* d_out, int out_size, void* d_ws, size_t ws_size,
                              hipStream_t stream) {
  (void)in_sizes; (void)n_in; (void)out_size;
  const float* x = (const float*)d_in[0];
  const float* wq = (const float*)d_in[1];
  const float* wk = (const float*)d_in[2];
  const float* wv = (const float*)d_in[3];
  const float* wo = (const float*)d_in[4];
  const float* bo = (const float*)d_in[5];
  float* y = (float*)d_out;

  char* base = (char*)d_ws;
  size_t off = 0;
  auto alloc = [&](size_t bytes) -> void* {
    void* p = base + off;
    off += (bytes + 255) & ~(size_t)255;
    return p;
  };
  __bf16* xb = (__bf16*)alloc((size_t)8192 * 512 * 2);
  __bf16* wqb = (__bf16*)alloc((size_t)8 * 512 * 512 * 2);
  __bf16* wkb = (__bf16*)alloc((size_t)8 * 512 * 512 * 2);
  __bf16* wvb = (__bf16*)alloc((size_t)8 * 512 * 512 * 2);
  __bf16* wob = (__bf16*)alloc((size_t)512 * 4096 * 2);
  float* ct = (float*)alloc((size_t)2048 * 256 * 4);
  float* st = (float*)alloc((size_t)2048 * 256 * 4);
  const size_t persist = off;

  int G = 0, lg = 0;
  for (int g = 8, l = 3; g >= 1; g >>= 1, --l) {
    size_t T = ((size_t)g * 4 * 2048 * 512 * 2 + 255) & ~(size_t)255;
    if (persist + 4 * T <= ws_size) { G = g; lg = l; break; }
  }
  if (G == 0) return;

  const int bhN = 4 * G;
  size_t T = ((size_t)G * 4 * 2048 * 512 * 2 + 255) & ~(size_t)255;
  size_t mlBytes = ((size_t)2 * bhN * 2048 * sizeof(float2) + 255) & ~(size_t)255;
  bool SPLIT = (G >= 2) && (persist + 5 * T + mlBytes <= ws_size);

  __bf16* Qb = (__bf16*)(base + persist);
  __bf16* Kb = (__bf16*)(base + persist + T);
  __bf16* VTb = (__bf16*)(base + persist + 2 * T);
  __bf16* Ob = (__bf16*)(base + persist + 3 * T);
  __bf16* O1b = SPLIT ? (__bf16*)(base + persist + 4 * T) : Ob;
  float2* Mlb = SPLIT ? (float2*)(base + persist + 5 * T) : (float2*)(base + persist);

  prep_k<<<14336, 256, 0, stream>>>(x, wq, wk, wv, wo, xb, wqb, wkb, wvb, wob, ct, st);

  const int n8 = bhN * 2048 * 64;
  for (int h0 = 0; h0 < 8; h0 += G) {
    qkv_gemm_k<<<dim3(64, 4, 3 * G), 256, 0, stream>>>(xb, wqb, wkb, wvb, ct, st,
                                                       Qb, Kb, VTb, G, lg, h0);
    if (SPLIT) {
      // In-run A/B: group 0 -> proven flashA; group 1 -> 2-barrier flashB.
      if (h0 == 0)
        flash_attn_k<1><<<dim3(32 * bhN), 512, 0, stream>>>(Qb, Kb, VTb, Ob, O1b, Mlb, G, lg);
      else
        flashB_k<<<dim3(32 * bhN), 512, 0, stream>>>(Qb, Kb, VTb, Ob, O1b, Mlb, G, lg);
      merge_k<<<(n8 + 255) / 256, 256, 0, stream>>>(Ob, O1b, Mlb, G, lg, n8);
    } else {
      flash_attn_k<0><<<dim3(16, bhN), 512, 0, stream>>>(Qb, Kb, VTb, Ob, O1b, Mlb, G, lg);
    }
    out_gemm_k<<<dim3(64, 8), 256, 0, stream>>>(Ob, wob + h0 * 512, bo, y, G, h0 == 0);
  }
}

// Round 16
// 630.083 us; speedup vs baseline: 1.8163x; 1.0203x over previous
//
#include <hip/hip_runtime.h>
#include <hip/hip_bf16.h>
#include <math.h>

// B=4, M=2048, D=512, H=8. Heads in groups of G (G=4 on this harness).

typedef __attribute__((ext_vector_type(8))) __bf16 bf16x8;
typedef __attribute__((ext_vector_type(4))) __bf16 bf16x4;
typedef __attribute__((ext_vector_type(4))) float f32x4;

#define MFMA16(a, b, c) __builtin_amdgcn_mfma_f32_16x16x32_bf16((a), (b), (c), 0, 0, 0)

__device__ __forceinline__ void g2l16(const void* g, void* l) {
  __builtin_amdgcn_global_load_lds((const __attribute__((address_space(1))) void*)g,
                                   (__attribute__((address_space(3))) void*)l, 16, 0, 0);
}

// ---------------- fused prep: all fp32->bf16 casts + RoPE tables ----------------
__global__ void prep_k(const float* __restrict__ x, const float* __restrict__ wq,
                       const float* __restrict__ wk, const float* __restrict__ wv,
                       const float* __restrict__ wo,
                       __bf16* __restrict__ xb, __bf16* __restrict__ wqb,
                       __bf16* __restrict__ wkb, __bf16* __restrict__ wvb,
                       __bf16* __restrict__ wob,
                       float* __restrict__ ct, float* __restrict__ st) {
  int i = blockIdx.x * 256 + threadIdx.x;
  if (i < 3145728) {
    const float* src;
    __bf16* dst;
    int off = i;
    if (i < 1048576) { src = x; dst = xb; }
    else if (i < 1572864) { src = wq; dst = wqb; off = i - 1048576; }
    else if (i < 2097152) { src = wk; dst = wkb; off = i - 1572864; }
    else if (i < 2621440) { src = wv; dst = wvb; off = i - 2097152; }
    else { src = wo; dst = wob; off = i - 2621440; }
    float4 f = reinterpret_cast<const float4*>(src)[off];
    bf16x4 o;
    o.x = (__bf16)f.x; o.y = (__bf16)f.y; o.z = (__bf16)f.z; o.w = (__bf16)f.w;
    reinterpret_cast<bf16x4*>(dst)[off] = o;
  } else {
    int idx = i - 3145728;  // 2048*256
    int m = idx >> 8, j = idx & 255;
    float e = (-2.0f * ((float)j - 1.0f) / 512.0f) * 13.287712379549449f;  // log2(1e4)
    float theta = exp2f(e);
    float ang = (float)m * theta;
    float s, c;
    sincosf(ang, &s, &c);
    ct[idx] = c;
    st[idx] = s;
  }
}

// ---------------- QKV projection: z = which*G + hl; V written directly transposed ----------------
__global__ __launch_bounds__(256, 2) void qkv_gemm_k(
    const __bf16* __restrict__ Xb,
    const __bf16* __restrict__ Wqb, const __bf16* __restrict__ Wkb, const __bf16* __restrict__ Wvb,
    const float* __restrict__ ct, const float* __restrict__ st,
    __bf16* __restrict__ Q, __bf16* __restrict__ K, __bf16* __restrict__ VT,
    int G, int lg, int h0) {
  const int z = blockIdx.z;
  const int which = z >> lg, hl = z & (G - 1);
  const int h = h0 + hl;
  const __bf16* W = (which == 0 ? Wqb : which == 1 ? Wkb : Wvb) + (size_t)h * 262144;

  const int mbase = blockIdx.x * 128;
  const int nbase = blockIdx.y * 128;

  __shared__ alignas(16) __bf16 As[128 * 64];
  __shared__ alignas(16) __bf16 Bs[128 * 64];

  const int tid = threadIdx.x;
  const int lane = tid & 63, wid = tid >> 6;
  const int wr = wid >> 1, wc = wid & 1;
  const int l15 = lane & 15, l4 = lane >> 4;

  f32x4 acc[4][4];
#pragma unroll
  for (int i = 0; i < 4; i++)
#pragma unroll
    for (int j = 0; j < 4; j++) acc[i][j] = f32x4{0.f, 0.f, 0.f, 0.f};

  for (int kt = 0; kt < 8; ++kt) {
    const int kb = kt * 64;
#pragma unroll
    for (int i = 0; i < 4; i++) {
      int chunk = i * 256 + tid;
      int row = chunk >> 3, col = (chunk & 7) * 8;
      g2l16(Xb + (size_t)(mbase + row) * 512 + kb + col, As + (i * 256 + (tid & ~63)) * 8);
    }
#pragma unroll
    for (int i = 0; i < 4; i++) {
      int chunk = i * 256 + tid;
      int row = chunk >> 3, col = (chunk & 7) * 8;
      g2l16(W + (size_t)(nbase + row) * 512 + kb + col, Bs + (i * 256 + (tid & ~63)) * 8);
    }
    __syncthreads();
#pragma unroll
    for (int kk = 0; kk < 2; ++kk) {
      bf16x8 a[4], b[4];
#pragma unroll
      for (int i = 0; i < 4; i++)
        a[i] = *reinterpret_cast<const bf16x8*>(As + (wr * 64 + i * 16 + l15) * 64 + kk * 32 + l4 * 8);
#pragma unroll
      for (int j = 0; j < 4; j++)
        b[j] = *reinterpret_cast<const bf16x8*>(Bs + (wc * 64 + j * 16 + l15) * 64 + kk * 32 + l4 * 8);
#pragma unroll
      for (int i = 0; i < 4; i++)
#pragma unroll
        for (int j = 0; j < 4; j++) acc[i][j] = MFMA16(a[i], b[j], acc[i][j]);
    }
    __syncthreads();
  }

  if (which == 2) {
    const int b_ = mbase >> 11;
    const int mloc = mbase & 2047;
    __bf16* Tgw = VT + (size_t)(b_ * G + hl) * 512 * 2048;
#pragma unroll
    for (int i = 0; i < 4; i++) {
#pragma unroll
      for (int j = 0; j < 4; j++) {
        const int col = nbase + wc * 64 + j * 16 + l15;
        const int m0 = mloc + wr * 64 + i * 16 + l4 * 4;
        bf16x4 pk;
        pk.x = (__bf16)acc[i][j][0];
        pk.y = (__bf16)acc[i][j][1];
        pk.z = (__bf16)acc[i][j][2];
        pk.w = (__bf16)acc[i][j][3];
        *reinterpret_cast<bf16x4*>(&Tgw[(size_t)col * 2048 + m0]) = pk;
      }
    }
  } else {
    __bf16* Out = which ? K : Q;
#pragma unroll
    for (int i = 0; i < 4; i++) {
#pragma unroll
      for (int j = 0; j < 4; j++) {
        const int col = nbase + wc * 64 + j * 16 + l15;
#pragma unroll
        for (int r = 0; r < 4; r++) {
          const int rowg = mbase + wr * 64 + i * 16 + l4 * 4 + r;
          const int b_ = rowg >> 11, m = rowg & 2047;
          float v = acc[i][j][r];
          float pv = __shfl_xor(v, 1, 64);
          float c = ct[m * 256 + (col >> 1)];
          float s = st[m * 256 + (col >> 1)];
          v = (col & 1) ? (v * c - pv * s) : (v * c + pv * s);
          Out[(size_t)((b_ * G + hl) * 2048 + m) * 512 + col] = (__bf16)v;
        }
      }
    }
  }
}

// ---------------- non-split fallback flash (R10/R14 proven) ----------------
__global__ __launch_bounds__(512) void flash_attn_k(
    const __bf16* __restrict__ Q, const __bf16* __restrict__ K, const __bf16* __restrict__ VT,
    __bf16* __restrict__ O0, int G, int lg) {
  const int bhN = 4 * G;
  const int L = blockIdx.x + 16 * blockIdx.y;
  const int half = L / (8 * bhN);
  const int r_ = L % (8 * bhN);
  const int bh = r_ % bhN;
  const int p_ = r_ / bhN;
  const int qblk = half ? (15 - p_) : p_;
  const int b = bh >> lg, hl = bh & (G - 1);
  const int tid = threadIdx.x, lane = tid & 63, wid = tid >> 6;
  const int l15 = lane & 15, l4 = lane >> 4;
  const int qw = qblk * 128 + wid * 16;

  __shared__ alignas(16) __bf16 Ks[32 * 512];
  __shared__ alignas(16) __bf16 Vts[512 * 32];
  __shared__ alignas(16) __bf16 Ps[8][16 * 32];

  const __bf16* Qg = Q + ((size_t)bh * 2048 + qw) * 512;
  const __bf16* Kg = K + (size_t)bh * 2048 * 512;
  const __bf16* Tg = VT + (size_t)bh * 512 * 2048;

  bf16x8 qf[16];
#pragma unroll
  for (int c = 0; c < 16; c++)
    qf[c] = *reinterpret_cast<const bf16x8*>(Qg + l15 * 512 + c * 32 + l4 * 8);

  f32x4 acc[32];
#pragma unroll
  for (int n = 0; n < 32; n++) acc[n] = f32x4{0.f, 0.f, 0.f, 0.f};
  float mrow[4] = {-INFINITY, -INFINITY, -INFINITY, -INFINITY};
  float lrow[4] = {0.f, 0.f, 0.f, 0.f};

  const float scale = 0.04419417382415922f;
  const int ntiles = qblk * 4 + 4;

  for (int kt = 0; kt < ntiles; ++kt) {
    const int kb = kt * 32;
#pragma unroll
    for (int i = 0; i < 4; i++) {
      int chunk = i * 512 + tid;
      int row = chunk >> 6, c16 = chunk & 63;
      g2l16(Kg + (size_t)(kb + row) * 512 + ((c16 ^ (row & 7)) << 3),
            Ks + (i * 512 + (tid & ~63)) * 8);
    }
#pragma unroll
    for (int i = 0; i < 4; i++) {
      int chunk = i * 512 + tid;
      int row = chunk >> 2, c4 = chunk & 3;
      g2l16(Tg + (size_t)row * 2048 + kb + ((c4 ^ ((row >> 1) & 3)) << 3),
            Vts + (i * 512 + (tid & ~63)) * 8);
    }
    __syncthreads();

    f32x4 sv0 = f32x4{0.f, 0.f, 0.f, 0.f}, sv1 = f32x4{0.f, 0.f, 0.f, 0.f};
#pragma unroll
    for (int c = 0; c < 16; c++) {
      const int off = c * 32 + l4 * 8;
      const int r0 = l15, r1 = 16 + l15;
      bf16x8 b0 = *reinterpret_cast<const bf16x8*>(Ks + r0 * 512 + (off ^ ((r0 & 7) << 3)));
      bf16x8 b1 = *reinterpret_cast<const bf16x8*>(Ks + r1 * 512 + (off ^ ((r1 & 7) << 3)));
      sv0 = MFMA16(qf[c], b0, sv0);
      sv1 = MFMA16(qf[c], b1, sv1);
    }

    float mx[4];
#pragma unroll
    for (int r = 0; r < 4; r++) {
      const int qg = qw + l4 * 4 + r;
      float s0 = sv0[r] * scale;
      float s1 = sv1[r] * scale;
      if (kb + l15 > qg) s0 = -INFINITY;
      if (kb + 16 + l15 > qg) s1 = -INFINITY;
      sv0[r] = s0; sv1[r] = s1;
      float m_ = fmaxf(s0, s1);
      m_ = fmaxf(m_, __shfl_xor(m_, 1, 64));
      m_ = fmaxf(m_, __shfl_xor(m_, 2, 64));
      m_ = fmaxf(m_, __shfl_xor(m_, 4, 64));
      m_ = fmaxf(m_, __shfl_xor(m_, 8, 64));
      mx[r] = m_;
    }
    bool need = (mx[0] > mrow[0] + 8.f) || (mx[1] > mrow[1] + 8.f) ||
                (mx[2] > mrow[2] + 8.f) || (mx[3] > mrow[3] + 8.f);
    if (__any(need)) {
      float alpha[4];
#pragma unroll
      for (int r = 0; r < 4; r++) {
        float mn = fmaxf(mrow[r], mx[r]);
        alpha[r] = __expf(mrow[r] - mn);
        lrow[r] *= alpha[r];
        mrow[r] = mn;
      }
#pragma unroll
      for (int n = 0; n < 32; n++) {
#pragma unroll
        for (int r = 0; r < 4; r++) acc[n][r] *= alpha[r];
      }
    }
#pragma unroll
    for (int r = 0; r < 4; r++) {
      float p0 = __expf(sv0[r] - mrow[r]);
      float p1 = __expf(sv1[r] - mrow[r]);
      float rs = p0 + p1;
      rs += __shfl_xor(rs, 1, 64);
      rs += __shfl_xor(rs, 2, 64);
      rs += __shfl_xor(rs, 4, 64);
      rs += __shfl_xor(rs, 8, 64);
      lrow[r] += rs;
      __bf16* P = &Ps[wid][0];
      P[(l4 * 4 + r) * 32 + l15] = (__bf16)p0;
      P[(l4 * 4 + r) * 32 + 16 + l15] = (__bf16)p1;
    }
    bf16x8 pf = *reinterpret_cast<const bf16x8*>(&Ps[wid][0] + l15 * 32 + l4 * 8);
#pragma unroll
    for (int n = 0; n < 32; n++) {
      const int row = n * 16 + l15;
      bf16x8 vb = *reinterpret_cast<const bf16x8*>(Vts + row * 32 + ((l4 * 8) ^ (((row >> 1) & 3) << 3)));
      acc[n] = MFMA16(pf, vb, acc[n]);
    }
    __syncthreads();
  }

#pragma unroll
  for (int r = 0; r < 4; r++) {
    const int qg = qw + l4 * 4 + r;
    const float inv = 1.0f / lrow[r];
    __bf16* Og = O0 + ((size_t)(b * 2048 + qg) * (512 * G) + hl * 512);
#pragma unroll
    for (int n = 0; n < 32; n++) Og[n * 16 + l15] = (__bf16)(acc[n][r] * inv);
  }
}

// ---------------- flashB: split-K, 2-barrier drain-covered schedule, padded Ps ----------------
// barrier1 drains K(kt) (covered by prev PV); V(kt) issued under QK+softmax; barrier2
// drains V(kt); K(kt+1) issued under PV. Ps stride 40 (80B rows): aligned b128 reads,
// conflict-free writes (was 4-way at stride 32).
__global__ __launch_bounds__(512) void flashB_k(
    const __bf16* __restrict__ Q, const __bf16* __restrict__ K, const __bf16* __restrict__ VT,
    __bf16* __restrict__ O0, __bf16* __restrict__ O1, float2* __restrict__ Ml,
    int G, int lg) {
  const int bhN = 4 * G;
  const int L = blockIdx.x;
  const int bh = L % bhN;
  const int s_ = L / bhN;  // 0..31
  const int ks = (s_ < 16) ? 0 : 1;
  const int qblk = ks ? (31 - s_) : s_;
  const int hn = 2 * qblk + 2;
  const int kt0 = ks * hn, kt1 = kt0 + hn;
  const int b = bh >> lg, hl = bh & (G - 1);
  const int tid = threadIdx.x, lane = tid & 63, wid = tid >> 6;
  const int l15 = lane & 15, l4 = lane >> 4;
  const int qw = qblk * 128 + wid * 16;

  __shared__ alignas(16) __bf16 Ks[32 * 512];
  __shared__ alignas(16) __bf16 Vts[512 * 32];
  __shared__ alignas(16) __bf16 Ps[8][16 * 40];  // stride 40: aligned + write-conflict-free

  const __bf16* Qg = Q + ((size_t)bh * 2048 + qw) * 512;
  const __bf16* Kg = K + (size_t)bh * 2048 * 512;
  const __bf16* Tg = VT + (size_t)bh * 512 * 2048;

  bf16x8 qf[16];
#pragma unroll
  for (int c = 0; c < 16; c++)
    qf[c] = *reinterpret_cast<const bf16x8*>(Qg + l15 * 512 + c * 32 + l4 * 8);

  f32x4 acc[32];
#pragma unroll
  for (int n = 0; n < 32; n++) acc[n] = f32x4{0.f, 0.f, 0.f, 0.f};
  float mrow[4] = {-INFINITY, -INFINITY, -INFINITY, -INFINITY};
  float lrow[4] = {0.f, 0.f, 0.f, 0.f};

  const float scale = 0.04419417382415922f;

  auto stageK = [&](int kt2) {
#pragma unroll
    for (int i = 0; i < 4; i++) {
      int chunk = i * 512 + tid;
      int row = chunk >> 6, c16 = chunk & 63;
      g2l16(Kg + (size_t)(kt2 * 32 + row) * 512 + ((c16 ^ (row & 7)) << 3),
            Ks + (i * 512 + (tid & ~63)) * 8);
    }
  };
  auto stageV = [&](int kt2) {
#pragma unroll
    for (int i = 0; i < 4; i++) {
      int chunk = i * 512 + tid;
      int row = chunk >> 2, c4 = chunk & 3;
      g2l16(Tg + (size_t)row * 2048 + kt2 * 32 + ((c4 ^ ((row >> 1) & 3)) << 3),
            Vts + (i * 512 + (tid & ~63)) * 8);
    }
  };

  stageK(kt0);

  for (int kt = kt0; kt < kt1; ++kt) {
    const int kb = kt * 32;
    __syncthreads();  // barrier1: PV(kt-1) done; drains K(kt) (covered by prev PV)
    stageV(kt);       // flies under QK + softmax

    f32x4 sv0 = f32x4{0.f, 0.f, 0.f, 0.f}, sv1 = f32x4{0.f, 0.f, 0.f, 0.f};
#pragma unroll
    for (int c = 0; c < 16; c++) {
      const int off = c * 32 + l4 * 8;
      const int r0 = l15, r1 = 16 + l15;
      bf16x8 b0 = *reinterpret_cast<const bf16x8*>(Ks + r0 * 512 + (off ^ ((r0 & 7) << 3)));
      bf16x8 b1 = *reinterpret_cast<const bf16x8*>(Ks + r1 * 512 + (off ^ ((r1 & 7) << 3)));
      sv0 = MFMA16(qf[c], b0, sv0);
      sv1 = MFMA16(qf[c], b1, sv1);
    }

    float mx[4];
#pragma unroll
    for (int r = 0; r < 4; r++) {
      const int qg = qw + l4 * 4 + r;
      float s0 = sv0[r] * scale;
      float s1 = sv1[r] * scale;
      if (kb + l15 > qg) s0 = -INFINITY;
      if (kb + 16 + l15 > qg) s1 = -INFINITY;
      sv0[r] = s0; sv1[r] = s1;
      float m_ = fmaxf(s0, s1);
      m_ = fmaxf(m_, __shfl_xor(m_, 1, 64));
      m_ = fmaxf(m_, __shfl_xor(m_, 2, 64));
      m_ = fmaxf(m_, __shfl_xor(m_, 4, 64));
      m_ = fmaxf(m_, __shfl_xor(m_, 8, 64));
      mx[r] = m_;
    }
    bool need = (mx[0] > mrow[0] + 8.f) || (mx[1] > mrow[1] + 8.f) ||
                (mx[2] > mrow[2] + 8.f) || (mx[3] > mrow[3] + 8.f);
    if (__any(need)) {
      float alpha[4];
#pragma unroll
      for (int r = 0; r < 4; r++) {
        float mn = fmaxf(mrow[r], mx[r]);
        alpha[r] = __expf(mrow[r] - mn);
        lrow[r] *= alpha[r];
        mrow[r] = mn;
      }
#pragma unroll
      for (int n = 0; n < 32; n++) {
#pragma unroll
        for (int r = 0; r < 4; r++) acc[n][r] *= alpha[r];
      }
    }
#pragma unroll
    for (int r = 0; r < 4; r++) {
      float p0 = __expf(sv0[r] - mrow[r]);
      float p1 = __expf(sv1[r] - mrow[r]);
      float rs = p0 + p1;
      rs += __shfl_xor(rs, 1, 64);
      rs += __shfl_xor(rs, 2, 64);
      rs += __shfl_xor(rs, 4, 64);
      rs += __shfl_xor(rs, 8, 64);
      lrow[r] += rs;
      __bf16* P = &Ps[wid][0];
      P[(l4 * 4 + r) * 40 + l15] = (__bf16)p0;
      P[(l4 * 4 + r) * 40 + 16 + l15] = (__bf16)p1;
    }

    __syncthreads();                   // barrier2: drains V(kt); all waves done with Ks
    if (kt + 1 < kt1) stageK(kt + 1);  // flies under PV

    bf16x8 pf = *reinterpret_cast<const bf16x8*>(&Ps[wid][0] + l15 * 40 + l4 * 8);
#pragma unroll
    for (int n = 0; n < 32; n++) {
      const int row = n * 16 + l15;
      bf16x8 vb = *reinterpret_cast<const bf16x8*>(Vts + row * 32 + ((l4 * 8) ^ (((row >> 1) & 3) << 3)));
      acc[n] = MFMA16(pf, vb, acc[n]);
    }
  }

  __bf16* Osel = ks ? O1 : O0;
#pragma unroll
  for (int r = 0; r < 4; r++) {
    const int qg = qw + l4 * 4 + r;
    const float inv = 1.0f / lrow[r];
    __bf16* Og = Osel + ((size_t)(b * 2048 + qg) * (512 * G) + hl * 512);
#pragma unroll
    for (int n = 0; n < 32; n++) Og[n * 16 + l15] = (__bf16)(acc[n][r] * inv);
    if (l15 == 0) Ml[ks * bhN * 2048 + bh * 2048 + qg] = make_float2(mrow[r], lrow[r]);
  }
}

// ---------------- split-K merge ----------------
__global__ void merge_k(__bf16* __restrict__ O0, const __bf16* __restrict__ O1,
                        const float2* __restrict__ Ml, int G, int lg, int n8) {
  int idx = blockIdx.x * 256 + threadIdx.x;
  if (idx >= n8) return;
  const int bhN = 4 * G;
  size_t flat = (size_t)idx * 8;
  int rowG = (int)(flat >> 9);
  int hl = rowG & (G - 1);
  int bm = rowG >> lg;
  int b = bm >> 11, m = bm & 2047;
  int bh = b * G + hl;
  float2 ml0 = Ml[bh * 2048 + m];
  float2 ml1 = Ml[bhN * 2048 + bh * 2048 + m];
  float mm = fmaxf(ml0.x, ml1.x);
  float w0 = __expf(ml0.x - mm) * ml0.y;
  bool h1 = (ml1.y > 0.f);
  float w1 = h1 ? __expf(ml1.x - mm) * ml1.y : 0.f;
  float inv = 1.f / (w0 + w1);
  float a0 = w0 * inv, a1 = w1 * inv;
  bf16x8 v0 = *reinterpret_cast<const bf16x8*>(O0 + flat);
  bf16x8 out;
  if (h1) {
    bf16x8 v1 = *reinterpret_cast<const bf16x8*>(O1 + flat);
#pragma unroll
    for (int j = 0; j < 8; j++) out[j] = (__bf16)(a0 * (float)v0[j] + a1 * (float)v1[j]);
  } else {
#pragma unroll
    for (int j = 0; j < 8; j++) out[j] = (__bf16)(a0 * (float)v0[j]);
  }
  *reinterpret_cast<bf16x8*>(O0 + flat) = out;
}

// ---------------- output projection: 128x64 tile ----------------
__global__ __launch_bounds__(256) void out_gemm_k(
    const __bf16* __restrict__ A, const __bf16* __restrict__ Wo,
    const float* __restrict__ bias, float* __restrict__ Y, int G, int first) {
  const int AS = 512 * G;
  const int mbase = blockIdx.x * 128, nbase = blockIdx.y * 64;
  __shared__ alignas(16) __bf16 As[128 * 64];
  __shared__ alignas(16) __bf16 Bs[64 * 64];
  const int tid = threadIdx.x;
  const int lane = tid & 63, wid = tid >> 6;
  const int wr = wid >> 1, wc = wid & 1;
  const int l15 = lane & 15, l4 = lane >> 4;

  f32x4 acc[4][2];
#pragma unroll
  for (int i = 0; i < 4; i++)
#pragma unroll
    for (int j = 0; j < 2; j++) acc[i][j] = f32x4{0.f, 0.f, 0.f, 0.f};

  const int nkt = 8 * G;
  for (int kt = 0; kt < nkt; ++kt) {
    const int kb = kt * 64;
#pragma unroll
    for (int i = 0; i < 4; i++) {
      int chunk = i * 256 + tid;
      int row = chunk >> 3, col = (chunk & 7) * 8;
      g2l16(A + (size_t)(mbase + row) * AS + kb + col, As + (i * 256 + (tid & ~63)) * 8);
    }
#pragma unroll
    for (int i = 0; i < 2; i++) {
      int chunk = i * 256 + tid;
      int row = chunk >> 3, col = (chunk & 7) * 8;
      g2l16(Wo + (size_t)(nbase + row) * 4096 + kb + col, Bs + (i * 256 + (tid & ~63)) * 8);
    }
    __syncthreads();
#pragma unroll
    for (int kk = 0; kk < 2; ++kk) {
      bf16x8 a[4], b[2];
#pragma unroll
      for (int i = 0; i < 4; i++)
        a[i] = *reinterpret_cast<const bf16x8*>(As + (wr * 64 + i * 16 + l15) * 64 + kk * 32 + l4 * 8);
#pragma unroll
      for (int j = 0; j < 2; j++)
        b[j] = *reinterpret_cast<const bf16x8*>(Bs + (wc * 32 + j * 16 + l15) * 64 + kk * 32 + l4 * 8);
#pragma unroll
      for (int i = 0; i < 4; i++)
#pragma unroll
        for (int j = 0; j < 2; j++) acc[i][j] = MFMA16(a[i], b[j], acc[i][j]);
    }
    __syncthreads();
  }

#pragma unroll
  for (int i = 0; i < 4; i++) {
#pragma unroll
    for (int j = 0; j < 2; j++) {
      const int col = nbase + wc * 32 + j * 16 + l15;
#pragma unroll
      for (int r = 0; r < 4; r++) {
        const int row = mbase + wr * 64 + i * 16 + l4 * 4 + r;
        float prev = first ? bias[col] : Y[(size_t)row * 512 + col];
        Y[(size_t)row * 512 + col] = prev + acc[i][j][r];
      }
    }
  }
}

extern "C" void kernel_launch(void* const* d_in, const int* in_sizes, int n_in,
                              void* d_out, int out_size, void* d_ws, size_t ws_size,
                              hipStream_t stream) {
  (void)in_sizes; (void)n_in; (void)out_size;
  const float* x = (const float*)d_in[0];
  const float* wq = (const float*)d_in[1];
  const float* wk = (const float*)d_in[2];
  const float* wv = (const float*)d_in[3];
  const float* wo = (const float*)d_in[4];
  const float* bo = (const float*)d_in[5];
  float* y = (float*)d_out;

  char* base = (char*)d_ws;
  size_t off = 0;
  auto alloc = [&](size_t bytes) -> void* {
    void* p = base + off;
    off += (bytes + 255) & ~(size_t)255;
    return p;
  };
  __bf16* xb = (__bf16*)alloc((size_t)8192 * 512 * 2);
  __bf16* wqb = (__bf16*)alloc((size_t)8 * 512 * 512 * 2);
  __bf16* wkb = (__bf16*)alloc((size_t)8 * 512 * 512 * 2);
  __bf16* wvb = (__bf16*)alloc((size_t)8 * 512 * 512 * 2);
  __bf16* wob = (__bf16*)alloc((size_t)512 * 4096 * 2);
  float* ct = (float*)alloc((size_t)2048 * 256 * 4);
  float* st = (float*)alloc((size_t)2048 * 256 * 4);
  const size_t persist = off;

  int G = 0, lg = 0;
  for (int g = 8, l = 3; g >= 1; g >>= 1, --l) {
    size_t T = ((size_t)g * 4 * 2048 * 512 * 2 + 255) & ~(size_t)255;
    if (persist + 4 * T <= ws_size) { G = g; lg = l; break; }
  }
  if (G == 0) return;

  const int bhN = 4 * G;
  size_t T = ((size_t)G * 4 * 2048 * 512 * 2 + 255) & ~(size_t)255;
  size_t mlBytes = ((size_t)2 * bhN * 2048 * sizeof(float2) + 255) & ~(size_t)255;
  bool SPLIT = (G >= 2) && (persist + 5 * T + mlBytes <= ws_size);

  __bf16* Qb = (__bf16*)(base + persist);
  __bf16* Kb = (__bf16*)(base + persist + T);
  __bf16* VTb = (__bf16*)(base + persist + 2 * T);
  __bf16* Ob = (__bf16*)(base + persist + 3 * T);
  __bf16* O1b = SPLIT ? (__bf16*)(base + persist + 4 * T) : Ob;
  float2* Mlb = SPLIT ? (float2*)(base + persist + 5 * T) : (float2*)(base + persist);

  prep_k<<<14336, 256, 0, stream>>>(x, wq, wk, wv, wo, xb, wqb, wkb, wvb, wob, ct, st);

  const int n8 = bhN * 2048 * 64;
  for (int h0 = 0; h0 < 8; h0 += G) {
    qkv_gemm_k<<<dim3(64, 4, 3 * G), 256, 0, stream>>>(xb, wqb, wkb, wvb, ct, st,
                                                       Qb, Kb, VTb, G, lg, h0);
    if (SPLIT) {
      flashB_k<<<dim3(32 * bhN), 512, 0, stream>>>(Qb, Kb, VTb, Ob, O1b, Mlb, G, lg);
      merge_k<<<(n8 + 255) / 256, 256, 0, stream>>>(Ob, O1b, Mlb, G, lg, n8);
    } else {
      flash_attn_k<<<dim3(16, bhN), 512, 0, stream>>>(Qb, Kb, VTb, Ob, G, lg);
    }
    out_gemm_k<<<dim3(64, 8), 256, 0, stream>>>(Ob, wob + h0 * 512, bo, y, G, h0 == 0);
  }
}